// Round 2
// 1823.422 us; speedup vs baseline: 1.9919x; 1.9919x over previous
//
#include <hip/hip_runtime.h>
#include <math.h>

#define TT 4096
#define BB 8
#define EE 1024
#define HH 8
#define DD 128
#define KK 64        // proj dim per head
#define PHI2 128     // 2K features per head
#define NPROJ 512    // H*K total pre-sincos width
#define CH 128
#define NC 32
#define NROWS 32768
#define EPSV 1e-6f

typedef float f32x4 __attribute__((ext_vector_type(4)));
typedef __bf16 bf16x8 __attribute__((ext_vector_type(8)));
typedef short short8 __attribute__((ext_vector_type(8)));

__device__ __forceinline__ unsigned short f2b(float f) {
  union { float f; unsigned int u; } v; v.f = f;
  unsigned int u = v.u;
  u += 0x7fffu + ((u >> 16) & 1u);
  return (unsigned short)(u >> 16);
}
__device__ __forceinline__ float b2f(unsigned short h) {
  union { float f; unsigned int u; } v; v.u = ((unsigned int)h) << 16;
  return v.f;
}

// async global->LDS, 16B per lane; lds ptr must be wave-uniform (HW writes base+lane*16).
__device__ __forceinline__ void stage16(const void* g, void* l) {
  __builtin_amdgcn_global_load_lds(
      (const __attribute__((address_space(1))) void*)g,
      (__attribute__((address_space(3))) void*)l, 16, 0, 0);
}

__device__ __forceinline__ bf16x8 ldfrag(const unsigned short* p) {
  short8 s = *(const short8*)p;
  return __builtin_bit_cast(bf16x8, s);
}

// ---- split fp32 -> bf16 hi + bf16 lo (residual), vectorized x4
__global__ __launch_bounds__(256) void split_kernel(
    const float* __restrict__ in, unsigned short* __restrict__ hi,
    unsigned short* __restrict__ lo, int n4)
{
  int stride = gridDim.x * 256;
  for (int i = blockIdx.x * 256 + threadIdx.x; i < n4; i += stride) {
    float4 v = ((const float4*)in)[i];
    ushort4 h, l;
    h.x = f2b(v.x); l.x = f2b(v.x - b2f(h.x));
    h.y = f2b(v.y); l.y = f2b(v.y - b2f(h.y));
    h.z = f2b(v.z); l.z = f2b(v.z - b2f(h.z));
    h.w = f2b(v.w); l.w = f2b(v.w - b2f(h.w));
    ((ushort4*)hi)[i] = h;
    ((ushort4*)lo)[i] = l;
  }
}

// ---- Weff[h*64+k][e] = sum_d s4*sigma[h,d]*rm[h,k,d]*W[h*128+d][e]; beff likewise from b.
__global__ __launch_bounds__(256) void weff_kernel(
    const float* __restrict__ rmat, const float* __restrict__ sigma,
    const float* __restrict__ W, const float* __restrict__ bvec,
    float* __restrict__ Weff, float* __restrict__ beff)
{
  __shared__ float rme[64][130];
  __shared__ float Wt[128][130];
  const int et = blockIdx.x;   // e-tile of 128
  const int h  = blockIdx.y;
  const int tid = threadIdx.x;
  const int e0 = et * 128;
  const float s4 = 0.29730177875068026f;  // 128^-0.25

  for (int f = tid; f < 64 * 32; f += 256) {
    int kk = f >> 5, d = (f & 31) * 4;
    float4 rv = *(const float4*)(rmat + ((size_t)(h * 64 + kk)) * 128 + d);
    const float* sg = sigma + h * 128 + d;
    rme[kk][d + 0] = rv.x * sg[0] * s4;
    rme[kk][d + 1] = rv.y * sg[1] * s4;
    rme[kk][d + 2] = rv.z * sg[2] * s4;
    rme[kk][d + 3] = rv.w * sg[3] * s4;
  }
  for (int f = tid; f < 128 * 32; f += 256) {
    int dd = f >> 5, e = (f & 31) * 4;
    *(float4*)&Wt[dd][e] = *(const float4*)(W + ((size_t)(h * 128 + dd)) * EE + e0 + e);
  }
  __syncthreads();
  const int nl = tid >> 2;
  const int el0 = (tid & 3) * 32;
  for (int e = 0; e < 32; ++e) {
    float acc = 0.f;
#pragma unroll
    for (int d = 0; d < 128; ++d)
      acc = fmaf(rme[nl][d], Wt[d][el0 + e], acc);
    Weff[(size_t)(h * 64 + nl) * EE + e0 + el0 + e] = acc;
  }
  if (et == 0 && tid < 64) {
    float acc = 0.f;
    for (int d = 0; d < 128; ++d)
      acc = fmaf(rme[tid][d], bvec[h * 128 + d], acc);
    beff[h * 64 + tid] = acc;
  }
}

// ---------------- MFMA GEMM: C[M,N] = A[M,K] @ W[N,K]^T + bias[N]
// fp32 split compensation fused in one K-loop:
//   NPASS=3: acc += Ahi*Whi + Ahi*Wlo + Alo*Whi   (fp32 A and W)
//   NPASS=2: acc += Ahi*Whi + Ahi*Wlo             (A already bf16)
// m97 structure: 128x128 tile, BK=32, 4 waves (2x2), 4x4 16x16x32 frags/wave,
// global_load_lds width=16, linear LDS.
template<int OUTBF16, int NPASS>
__global__ __launch_bounds__(256) void gemm_mfma(
    const unsigned short* __restrict__ Ahi, const unsigned short* __restrict__ Alo,
    const unsigned short* __restrict__ Whi, const unsigned short* __restrict__ Wlo,
    const float* __restrict__ bias, void* __restrict__ Cout, int M, int N, int Kd)
{
  __shared__ __align__(16) unsigned short Ahs[128 * 32];
  __shared__ __align__(16) unsigned short Whs[128 * 32];
  __shared__ __align__(16) unsigned short Wls[128 * 32];
  __shared__ __align__(16) unsigned short Als[128 * 32];
  const int tid = threadIdx.x;
  const int w = tid >> 6, l = tid & 63;
  const int m0 = blockIdx.x * 128, n0 = blockIdx.y * 128;
  const int wm = (w >> 1) * 64, wn = (w & 1) * 64;
  const int rowA = tid >> 2, ko = (tid & 3) * 8;  // staging: 16B per lane

  f32x4 acc[4][4] = {};

  // wave-uniform LDS staging bases: issue s of tile X covers bytes [s*4096 + w*1024, +1024)
  const int sb0 = w * 512, sb1 = 2048 + w * 512;

  // fragment bases: row = tile_row, k-slot = (l>>4)*8..+8 (same bijection for A and W)
  const int fA = (wm + (l & 15)) * 32 + (l >> 4) * 8;
  const int fW = (wn + (l & 15)) * 32 + (l >> 4) * 8;

  const unsigned short* gah0 = Ahi + (size_t)(m0 + rowA) * Kd + ko;
  const unsigned short* gah1 = Ahi + (size_t)(m0 + 64 + rowA) * Kd + ko;
  const unsigned short* gwh0 = Whi + (size_t)(n0 + rowA) * Kd + ko;
  const unsigned short* gwh1 = Whi + (size_t)(n0 + 64 + rowA) * Kd + ko;
  const unsigned short* gwl0 = Wlo + (size_t)(n0 + rowA) * Kd + ko;
  const unsigned short* gwl1 = Wlo + (size_t)(n0 + 64 + rowA) * Kd + ko;
  const unsigned short* gal0 = nullptr;
  const unsigned short* gal1 = nullptr;
  if (NPASS == 3) {
    gal0 = Alo + (size_t)(m0 + rowA) * Kd + ko;
    gal1 = Alo + (size_t)(m0 + 64 + rowA) * Kd + ko;
  }

#pragma unroll 1
  for (int kt = 0; kt < Kd; kt += 32) {
    __syncthreads();  // previous iter's frag reads done before overwrite
    stage16(gah0 + kt, Ahs + sb0);
    stage16(gah1 + kt, Ahs + sb1);
    stage16(gwh0 + kt, Whs + sb0);
    stage16(gwh1 + kt, Whs + sb1);
    stage16(gwl0 + kt, Wls + sb0);
    stage16(gwl1 + kt, Wls + sb1);
    if (NPASS == 3) {
      stage16(gal0 + kt, Als + sb0);
      stage16(gal1 + kt, Als + sb1);
    }
    __syncthreads();  // compiler drains vmcnt before barrier -> staged tile visible
    bf16x8 ah[4], wh[4], wl[4];
#pragma unroll
    for (int i = 0; i < 4; ++i) {
      ah[i] = ldfrag(Ahs + fA + i * 512);
      wh[i] = ldfrag(Whs + fW + i * 512);
      wl[i] = ldfrag(Wls + fW + i * 512);
    }
#pragma unroll
    for (int i = 0; i < 4; ++i)
#pragma unroll
      for (int j = 0; j < 4; ++j)
        acc[i][j] = __builtin_amdgcn_mfma_f32_16x16x32_bf16(ah[i], wh[j], acc[i][j], 0, 0, 0);
#pragma unroll
    for (int i = 0; i < 4; ++i)
#pragma unroll
      for (int j = 0; j < 4; ++j)
        acc[i][j] = __builtin_amdgcn_mfma_f32_16x16x32_bf16(ah[i], wl[j], acc[i][j], 0, 0, 0);
    if (NPASS == 3) {
      bf16x8 al[4];
#pragma unroll
      for (int i = 0; i < 4; ++i) al[i] = ldfrag(Als + fA + i * 512);
#pragma unroll
      for (int i = 0; i < 4; ++i)
#pragma unroll
        for (int j = 0; j < 4; ++j)
          acc[i][j] = __builtin_amdgcn_mfma_f32_16x16x32_bf16(al[i], wh[j], acc[i][j], 0, 0, 0);
    }
  }

  // epilogue: C row = m0+wm+i*16+(l>>4)*4+r ; col = n0+wn+j*16+(l&15)  [HW-verified C/D map]
  const int cl = l & 15, rg = (l >> 4) * 4;
  float bvv[4];
#pragma unroll
  for (int j = 0; j < 4; ++j) bvv[j] = bias[n0 + wn + j * 16 + cl];
#pragma unroll
  for (int i = 0; i < 4; ++i) {
    const int row = m0 + wm + i * 16 + rg;
#pragma unroll
    for (int r = 0; r < 4; ++r) {
#pragma unroll
      for (int j = 0; j < 4; ++j) {
        float v = acc[i][j][r] + bvv[j];
        if (OUTBF16) {
          ((unsigned short*)Cout)[(size_t)(row + r) * N + n0 + wn + j * 16 + cl] = f2b(v);
        } else {
          ((float*)Cout)[(size_t)(row + r) * N + n0 + wn + j * 16 + cl] = v;
        }
      }
    }
  }
}

// ---------------- pass1: per (c,b,h): S_c[f][d] = sum_j phi_k[j][f]*v[j][d]; z_c[f]
__global__ __launch_bounds__(256) void pass1_kernel(
    const float* __restrict__ Pk, const unsigned short* __restrict__ Vb,
    unsigned short* __restrict__ Sb, float* __restrict__ Z)
{
  __shared__ float kt[16][132];
  __shared__ float vt[16][132];
  const int c = blockIdx.x, b = blockIdx.y, h = blockIdx.z;
  const int tid = threadIdx.x;
  const int ty = tid >> 4, tx = tid & 15;
  float acc[8][8];
#pragma unroll
  for (int i = 0; i < 8; ++i)
#pragma unroll
    for (int j = 0; j < 8; ++j) acc[i][j] = 0.f;
  float zacc[8] = {0.f, 0.f, 0.f, 0.f, 0.f, 0.f, 0.f, 0.f};

  for (int jt = 0; jt < CH; jt += 16) {
    __syncthreads();
    {
      int jj = tid >> 4, q = tid & 15;
      size_t row = (size_t)((c * CH + jt + jj) * BB + b);
      float4 pv = *(const float4*)(Pk + row * NPROJ + h * KK + q * 4);
      float sv, cv;
      sincosf(pv.x, &sv, &cv);
      kt[jj][q * 4 + 0] = sv * 0.125f; kt[jj][64 + q * 4 + 0] = cv * 0.125f;
      sincosf(pv.y, &sv, &cv);
      kt[jj][q * 4 + 1] = sv * 0.125f; kt[jj][64 + q * 4 + 1] = cv * 0.125f;
      sincosf(pv.z, &sv, &cv);
      kt[jj][q * 4 + 2] = sv * 0.125f; kt[jj][64 + q * 4 + 2] = cv * 0.125f;
      sincosf(pv.w, &sv, &cv);
      kt[jj][q * 4 + 3] = sv * 0.125f; kt[jj][64 + q * 4 + 3] = cv * 0.125f;
      const unsigned short* vp = Vb + row * EE + h * DD + q * 8;
      ushort4 v0 = *(const ushort4*)vp;
      ushort4 v1 = *(const ushort4*)(vp + 4);
      vt[jj][q * 8 + 0] = b2f(v0.x); vt[jj][q * 8 + 1] = b2f(v0.y);
      vt[jj][q * 8 + 2] = b2f(v0.z); vt[jj][q * 8 + 3] = b2f(v0.w);
      vt[jj][q * 8 + 4] = b2f(v1.x); vt[jj][q * 8 + 5] = b2f(v1.y);
      vt[jj][q * 8 + 6] = b2f(v1.z); vt[jj][q * 8 + 7] = b2f(v1.w);
    }
    __syncthreads();
#pragma unroll
    for (int jj = 0; jj < 16; ++jj) {
      float a[8], bb[8];
      *(float4*)&a[0] = *(const float4*)&kt[jj][ty * 8];
      *(float4*)&a[4] = *(const float4*)&kt[jj][ty * 8 + 4];
      *(float4*)&bb[0] = *(const float4*)&vt[jj][tx * 8];
      *(float4*)&bb[4] = *(const float4*)&vt[jj][tx * 8 + 4];
#pragma unroll
      for (int i = 0; i < 8; ++i)
#pragma unroll
        for (int j = 0; j < 8; ++j)
          acc[i][j] = fmaf(a[i], bb[j], acc[i][j]);
      if (tx == 0) {
#pragma unroll
        for (int i = 0; i < 8; ++i) zacc[i] += a[i];
      }
    }
  }
  const int bh = b * HH + h;
  unsigned short* sp = Sb + ((size_t)bh * NC + c) * (CH * DD);
#pragma unroll
  for (int i = 0; i < 8; ++i) {
    unsigned short* rowp = sp + (ty * 8 + i) * DD + tx * 8;
    ushort4 o0 = make_ushort4(f2b(acc[i][0]), f2b(acc[i][1]), f2b(acc[i][2]), f2b(acc[i][3]));
    ushort4 o1 = make_ushort4(f2b(acc[i][4]), f2b(acc[i][5]), f2b(acc[i][6]), f2b(acc[i][7]));
    *(ushort4*)rowp = o0;
    *(ushort4*)(rowp + 4) = o1;
  }
  if (tx == 0) {
    float* zp = Z + ((size_t)bh * NC + c) * CH + ty * 8;
#pragma unroll
    for (int i = 0; i < 8; ++i) zp[i] = zacc[i];
  }
}

// ---------------- scan: exclusive prefix over chunks (S bf16, Z fp32)
__global__ __launch_bounds__(256) void scan_kernel(unsigned short* __restrict__ Sb,
                                                   float* __restrict__ Z)
{
  int gid = blockIdx.x * 256 + threadIdx.x;
  const int SE = 64 * CH * DD;  // 1048576 scan columns for S
  if (gid < SE) {
    int bh = gid >> 14, fd = gid & 16383;
    unsigned short* p = Sb + (size_t)bh * NC * 16384 + fd;
    float run = 0.f;
#pragma unroll
    for (int cc = 0; cc < NC; ++cc) {
      float t = b2f(p[(size_t)cc * 16384]);
      p[(size_t)cc * 16384] = f2b(run);
      run += t;
    }
  } else {
    int zi = gid - SE;
    if (zi < 64 * CH) {
      int bh = zi >> 7, f = zi & 127;
      float* p = Z + (size_t)bh * NC * CH + f;
      float run = 0.f;
#pragma unroll
      for (int cc = 0; cc < NC; ++cc) {
        float t = p[cc * CH];
        p[cc * CH] = run;
        run += t;
      }
    }
  }
}

// ---------------- attn: per (c,b,h); S,Z hold exclusive prefixes
__global__ __launch_bounds__(256) void attn_kernel(
    const float* __restrict__ Pq, const float* __restrict__ Pk,
    const unsigned short* __restrict__ Vb, const unsigned short* __restrict__ Sb,
    const float* __restrict__ Z, unsigned short* __restrict__ Ob)
{
  __shared__ float sc[128][132];
  __shared__ float tA[16][132];
  __shared__ float tB[16][132];
  __shared__ float den[128];
  __shared__ float zs[128];
  const int c = blockIdx.x, b = blockIdx.y, h = blockIdx.z;
  const int tid = threadIdx.x;
  const int ty = tid >> 4, tx = tid & 15;
  const int bh = b * HH + h;

  if (tid < 128) zs[tid] = Z[((size_t)bh * NC + c) * CH + tid];

  float acc[8][8];
#pragma unroll
  for (int i = 0; i < 8; ++i)
#pragma unroll
    for (int j = 0; j < 8; ++j) acc[i][j] = 0.f;
  float denz[8] = {0.f, 0.f, 0.f, 0.f, 0.f, 0.f, 0.f, 0.f};

  // phase A: scores = phi_q @ phi_k^T over 128 features; denz = phi_q . z
  for (int ft = 0; ft < PHI2; ft += 16) {
    __syncthreads();
    const int cb0 = (ft < 64) ? ft : (ft - 64);
    const bool issin = (ft < 64);
#pragma unroll
    for (int s = 0; s < 2; ++s) {
      int idx = tid + s * 256;
      int i = idx >> 2, fq = idx & 3;
      size_t row = (size_t)((c * CH + i) * BB + b);
      float4 qv = *(const float4*)(Pq + row * NPROJ + h * KK + cb0 + fq * 4);
      float4 kv = *(const float4*)(Pk + row * NPROJ + h * KK + cb0 + fq * 4);
      float sv, cv;
      sincosf(qv.x, &sv, &cv); tA[fq * 4 + 0][i] = (issin ? sv : cv) * 0.125f;
      sincosf(qv.y, &sv, &cv); tA[fq * 4 + 1][i] = (issin ? sv : cv) * 0.125f;
      sincosf(qv.z, &sv, &cv); tA[fq * 4 + 2][i] = (issin ? sv : cv) * 0.125f;
      sincosf(qv.w, &sv, &cv); tA[fq * 4 + 3][i] = (issin ? sv : cv) * 0.125f;
      sincosf(kv.x, &sv, &cv); tB[fq * 4 + 0][i] = (issin ? sv : cv) * 0.125f;
      sincosf(kv.y, &sv, &cv); tB[fq * 4 + 1][i] = (issin ? sv : cv) * 0.125f;
      sincosf(kv.z, &sv, &cv); tB[fq * 4 + 2][i] = (issin ? sv : cv) * 0.125f;
      sincosf(kv.w, &sv, &cv); tB[fq * 4 + 3][i] = (issin ? sv : cv) * 0.125f;
    }
    __syncthreads();
#pragma unroll
    for (int ff = 0; ff < 16; ++ff) {
      float a[8], bb[8];
      *(float4*)&a[0] = *(const float4*)&tA[ff][ty * 8];
      *(float4*)&a[4] = *(const float4*)&tA[ff][ty * 8 + 4];
      *(float4*)&bb[0] = *(const float4*)&tB[ff][tx * 8];
      *(float4*)&bb[4] = *(const float4*)&tB[ff][tx * 8 + 4];
#pragma unroll
      for (int i = 0; i < 8; ++i)
#pragma unroll
        for (int j = 0; j < 8; ++j)
          acc[i][j] = fmaf(a[i], bb[j], acc[i][j]);
      if (tx == 0) {
        float zv = zs[ft + ff];
#pragma unroll
        for (int i = 0; i < 8; ++i) denz[i] = fmaf(a[i], zv, denz[i]);
      }
    }
  }
  __syncthreads();
#pragma unroll
  for (int i = 0; i < 8; ++i) {
    int gi = ty * 8 + i;
#pragma unroll
    for (int j = 0; j < 8; ++j) {
      int gj = tx * 8 + j;
      sc[gi][gj] = (gj <= gi) ? acc[i][j] : 0.f;
    }
  }
  if (tx == 0) {
#pragma unroll
    for (int i = 0; i < 8; ++i) den[ty * 8 + i] = denz[i];
  }
  __syncthreads();
  {
    int i = tid >> 1;
    int j0 = (tid & 1) * 64;
    float ssum = 0.f;
#pragma unroll
    for (int j = 0; j < 64; j += 4) {
      float4 sv = *(const float4*)&sc[i][j0 + j];
      ssum += sv.x + sv.y + sv.z + sv.w;
    }
    ssum += __shfl_xor(ssum, 1);
    if ((tid & 1) == 0) den[i] += ssum;
  }

  // phase B: num = sc @ v + phi_q @ S_prefix
  float nacc[8][8];
#pragma unroll
  for (int i = 0; i < 8; ++i)
#pragma unroll
    for (int j = 0; j < 8; ++j) nacc[i][j] = 0.f;

  for (int jt = 0; jt < CH; jt += 16) {
    __syncthreads();
    {
      int jj = tid >> 4, dq = tid & 15;
      size_t row = (size_t)((c * CH + jt + jj) * BB + b);
      const unsigned short* vp = Vb + row * EE + h * DD + dq * 8;
      ushort4 v0 = *(const ushort4*)vp;
      ushort4 v1 = *(const ushort4*)(vp + 4);
      tB[jj][dq * 8 + 0] = b2f(v0.x); tB[jj][dq * 8 + 1] = b2f(v0.y);
      tB[jj][dq * 8 + 2] = b2f(v0.z); tB[jj][dq * 8 + 3] = b2f(v0.w);
      tB[jj][dq * 8 + 4] = b2f(v1.x); tB[jj][dq * 8 + 5] = b2f(v1.y);
      tB[jj][dq * 8 + 6] = b2f(v1.z); tB[jj][dq * 8 + 7] = b2f(v1.w);
    }
    __syncthreads();
#pragma unroll
    for (int jj = 0; jj < 16; ++jj) {
      int j = jt + jj;
      float a[8], bb[8];
#pragma unroll
      for (int i = 0; i < 8; ++i) a[i] = sc[ty * 8 + i][j];
      *(float4*)&bb[0] = *(const float4*)&tB[jj][tx * 8];
      *(float4*)&bb[4] = *(const float4*)&tB[jj][tx * 8 + 4];
#pragma unroll
      for (int i = 0; i < 8; ++i)
#pragma unroll
        for (int jd = 0; jd < 8; ++jd)
          nacc[i][jd] = fmaf(a[i], bb[jd], nacc[i][jd]);
    }
  }
  const unsigned short* S0 = Sb + ((size_t)bh * NC + c) * (CH * DD);
  for (int ft = 0; ft < PHI2; ft += 16) {
    __syncthreads();
    const int cb0 = (ft < 64) ? ft : (ft - 64);
    const bool issin = (ft < 64);
#pragma unroll
    for (int s = 0; s < 2; ++s) {
      int idx = tid + s * 256;
      int i = idx >> 2, fq = idx & 3;
      size_t row = (size_t)((c * CH + i) * BB + b);
      float4 qv = *(const float4*)(Pq + row * NPROJ + h * KK + cb0 + fq * 4);
      float sv, cv;
      sincosf(qv.x, &sv, &cv); tA[fq * 4 + 0][i] = (issin ? sv : cv) * 0.125f;
      sincosf(qv.y, &sv, &cv); tA[fq * 4 + 1][i] = (issin ? sv : cv) * 0.125f;
      sincosf(qv.z, &sv, &cv); tA[fq * 4 + 2][i] = (issin ? sv : cv) * 0.125f;
      sincosf(qv.w, &sv, &cv); tA[fq * 4 + 3][i] = (issin ? sv : cv) * 0.125f;
      int jj = idx >> 5, d = (idx & 31) * 4;
      ushort4 s4v = *(const ushort4*)(S0 + (size_t)(ft + jj) * DD + d);
      tB[jj][d + 0] = b2f(s4v.x); tB[jj][d + 1] = b2f(s4v.y);
      tB[jj][d + 2] = b2f(s4v.z); tB[jj][d + 3] = b2f(s4v.w);
    }
    __syncthreads();
#pragma unroll
    for (int ff = 0; ff < 16; ++ff) {
      float a[8], bb[8];
      *(float4*)&a[0] = *(const float4*)&tA[ff][ty * 8];
      *(float4*)&a[4] = *(const float4*)&tA[ff][ty * 8 + 4];
      *(float4*)&bb[0] = *(const float4*)&tB[ff][tx * 8];
      *(float4*)&bb[4] = *(const float4*)&tB[ff][tx * 8 + 4];
#pragma unroll
      for (int i = 0; i < 8; ++i)
#pragma unroll
        for (int jd = 0; jd < 8; ++jd)
          nacc[i][jd] = fmaf(a[i], bb[jd], nacc[i][jd]);
    }
  }
#pragma unroll
  for (int i = 0; i < 8; ++i) {
    int gi = ty * 8 + i;
    float inv = 1.0f / fmaxf(den[gi], EPSV);
    unsigned short* op = Ob + (size_t)((c * CH + gi) * BB + b) * EE + h * DD + tx * 8;
    ushort4 o0 = make_ushort4(f2b(nacc[i][0] * inv), f2b(nacc[i][1] * inv),
                              f2b(nacc[i][2] * inv), f2b(nacc[i][3] * inv));
    ushort4 o1 = make_ushort4(f2b(nacc[i][4] * inv), f2b(nacc[i][5] * inv),
                              f2b(nacc[i][6] * inv), f2b(nacc[i][7] * inv));
    *(ushort4*)op = o0;
    *(ushort4*)(op + 4) = o1;
  }
}

extern "C" void kernel_launch(void* const* d_in, const int* in_sizes, int n_in,
                              void* d_out, int out_size, void* d_ws, size_t ws_size,
                              hipStream_t stream)
{
  const float* x     = (const float*)d_in[0];
  const float* rmat  = (const float*)d_in[1];
  const float* Wq    = (const float*)d_in[2];
  const float* bq    = (const float*)d_in[3];
  const float* Wk    = (const float*)d_in[4];
  const float* bk    = (const float*)d_in[5];
  const float* Wv    = (const float*)d_in[6];
  const float* bv    = (const float*)d_in[7];
  const float* Wo    = (const float*)d_in[8];
  const float* bo    = (const float*)d_in[9];
  const float* sigma = (const float*)d_in[10];
  float* out = (float*)d_out;

  // ---- workspace layout (256 MiB):
  //   [0,   64Mi): pq_p fp32   (after attn: Woh/Wol bf16 alias at [0,4Mi))
  //   [64, 128Mi): pk_p fp32
  //   [128,192Mi): Vb bf16
  //   [192,256Mi): Ob bf16; pre-attn aliases: Weq/Wek fp32, biases, all bf16 weight splits
  // ---- d_out (128 MiB) as scratch:
  //   phases 1-3: xhi bf16 [0,64Mi), xlo bf16 [64,128Mi)
  //   phases 4-5: Sb bf16 [0,64Mi), Z fp32 [64Mi,66Mi)   (xhi/xlo dead by then)
  char* wsb = (char*)d_ws;
  float* pq_p = (float*)wsb;
  float* pk_p = (float*)(wsb + (64LL << 20));
  unsigned short* Vb = (unsigned short*)(wsb + (128LL << 20));
  unsigned short* Ob = (unsigned short*)(wsb + (192LL << 20));
  float* Weq = (float*)(wsb + (192LL << 20));
  float* Wek = (float*)(wsb + (194LL << 20));
  float* beq = (float*)(wsb + (196LL << 20));
  float* bek = (float*)(wsb + (196LL << 20) + 65536);
  unsigned short* Weqh = (unsigned short*)(wsb + (197LL << 20));
  unsigned short* Weql = (unsigned short*)(wsb + (198LL << 20));
  unsigned short* Wekh = (unsigned short*)(wsb + (199LL << 20));
  unsigned short* Wekl = (unsigned short*)(wsb + (200LL << 20));
  unsigned short* Wvh  = (unsigned short*)(wsb + (201LL << 20));
  unsigned short* Wvl  = (unsigned short*)(wsb + (203LL << 20));
  unsigned short* Woh  = (unsigned short*)wsb;              // cast after attn (pq dead)
  unsigned short* Wol  = (unsigned short*)(wsb + (2LL << 20));

  char* ob = (char*)d_out;
  unsigned short* xhi = (unsigned short*)ob;
  unsigned short* xlo = (unsigned short*)(ob + (64LL << 20));
  unsigned short* Sb = (unsigned short*)d_out;
  float* Zf = (float*)(ob + (64LL << 20));

  dim3 bt(256);
  // phase 1: casts + effective projection weights
  hipLaunchKernelGGL(split_kernel, dim3(2048), bt, 0, stream, x, xhi, xlo, NROWS * EE / 4);
  hipLaunchKernelGGL(weff_kernel, dim3(8, 8), bt, 0, stream, rmat, sigma, Wq, bq, Weq, beq);
  hipLaunchKernelGGL(weff_kernel, dim3(8, 8), bt, 0, stream, rmat, sigma, Wk, bk, Wek, bek);
  hipLaunchKernelGGL(split_kernel, dim3(512), bt, 0, stream, Weq, Weqh, Weql, NPROJ * EE / 4);
  hipLaunchKernelGGL(split_kernel, dim3(512), bt, 0, stream, Wek, Wekh, Wekl, NPROJ * EE / 4);
  hipLaunchKernelGGL(split_kernel, dim3(1024), bt, 0, stream, Wv, Wvh, Wvl, EE * EE / 4);
  // phase 2: Q/K pre-sincos projections (split-compensated, fp32 out)
  hipLaunchKernelGGL((gemm_mfma<0, 3>), dim3(NROWS / 128, NPROJ / 128), bt, 0, stream,
                     xhi, xlo, Weqh, Weql, beq, (void*)pq_p, NROWS, NPROJ, EE);
  hipLaunchKernelGGL((gemm_mfma<0, 3>), dim3(NROWS / 128, NPROJ / 128), bt, 0, stream,
                     xhi, xlo, Wekh, Wekl, bek, (void*)pk_p, NROWS, NPROJ, EE);
  // phase 3: V projection (split-compensated, bf16 out)
  hipLaunchKernelGGL((gemm_mfma<1, 3>), dim3(NROWS / 128, EE / 128), bt, 0, stream,
                     xhi, xlo, Wvh, Wvl, bv, (void*)Vb, NROWS, EE, EE);
  // phase 4-5: chunked linear attention (unchanged)
  hipLaunchKernelGGL(pass1_kernel, dim3(NC, BB, HH), bt, 0, stream, pk_p, Vb, Sb, Zf);
  hipLaunchKernelGGL(scan_kernel, dim3((64 * CH * DD + 64 * CH + 255) / 256), bt, 0, stream, Sb, Zf);
  hipLaunchKernelGGL(attn_kernel, dim3(NC, BB, HH), bt, 0, stream, pq_p, pk_p, Vb, Sb, Zf, Ob);
  // phase 6: output projection (A already bf16; 2-term split on Wo, fp32 out)
  hipLaunchKernelGGL(split_kernel, dim3(1024), bt, 0, stream, Wo, Woh, Wol, EE * EE / 4);
  hipLaunchKernelGGL((gemm_mfma<0, 2>), dim3(NROWS / 128, EE / 128), bt, 0, stream,
                     Ob, (const unsigned short*)0, Woh, Wol, bo, (void*)out, NROWS, EE, EE);
}

// Round 4
// 1370.099 us; speedup vs baseline: 2.6509x; 1.3309x over previous
//
#include <hip/hip_runtime.h>
#include <math.h>

#define TT 4096
#define BB 8
#define EE 1024
#define HH 8
#define DD 128
#define KK 64        // proj dim per head
#define PHI2 128     // 2K features per head
#define NPROJ 512    // H*K total pre-sincos width
#define CH 128
#define NC 32
#define NROWS 32768
#define EPSV 1e-6f

typedef float f32x4 __attribute__((ext_vector_type(4)));
typedef __bf16 bf16x8 __attribute__((ext_vector_type(8)));
typedef unsigned short u16x8 __attribute__((ext_vector_type(8)));
typedef unsigned short u16x4 __attribute__((ext_vector_type(4)));

__device__ __forceinline__ unsigned short f2b(float f) {
  union { float f; unsigned int u; } v; v.f = f;
  unsigned int u = v.u;
  u += 0x7fffu + ((u >> 16) & 1u);
  return (unsigned short)(u >> 16);
}
__device__ __forceinline__ float b2f(unsigned short h) {
  union { float f; unsigned int u; } v; v.u = ((unsigned int)h) << 16;
  return v.f;
}

// async global->LDS, 16B per lane; lds ptr must be wave-uniform (HW writes base+lane*16).
__device__ __forceinline__ void stage16(const void* g, void* l) {
  __builtin_amdgcn_global_load_lds(
      (const __attribute__((address_space(1))) void*)g,
      (__attribute__((address_space(3))) void*)l, 16, 0, 0);
}

__device__ __forceinline__ bf16x8 ldfrag(const unsigned short* p) {  // 16B-aligned
  u16x8 s = *(const u16x8*)p;
  return __builtin_bit_cast(bf16x8, s);
}
__device__ __forceinline__ bf16x8 ldfrag64(const unsigned short* p) {  // 8B-aligned (pitch-132 LDS)
  u16x4 a = *(const u16x4*)p;
  u16x4 b = *(const u16x4*)(p + 4);
  u16x8 v = {a[0], a[1], a[2], a[3], b[0], b[1], b[2], b[3]};
  return __builtin_bit_cast(bf16x8, v);
}

// stream-stage [128 rows][32 cols] bf16 from global (row stride rstride shorts)
// into LDS pitch 40 (80B rows, 16B-aligned). all 256 threads.
__device__ __forceinline__ void stage_rs(const unsigned short* gbase, size_t rstride,
                                         unsigned short* lds, int tid)
{
  int r = tid >> 1, c0 = (tid & 1) * 16;
  const unsigned short* gp = gbase + (size_t)r * rstride + c0;
  u16x8 v0 = *(const u16x8*)gp;
  u16x8 v1 = *(const u16x8*)(gp + 8);
  *(u16x8*)(lds + r * 40 + c0) = v0;
  *(u16x8*)(lds + r * 40 + c0 + 8) = v1;
}

// ---- split fp32 -> bf16 hi + bf16 lo (residual), vectorized x4
__global__ __launch_bounds__(256) void split_kernel(
    const float* __restrict__ in, unsigned short* __restrict__ hi,
    unsigned short* __restrict__ lo, int n4)
{
  int stride = gridDim.x * 256;
  for (int i = blockIdx.x * 256 + threadIdx.x; i < n4; i += stride) {
    float4 v = ((const float4*)in)[i];
    ushort4 h, l;
    h.x = f2b(v.x); l.x = f2b(v.x - b2f(h.x));
    h.y = f2b(v.y); l.y = f2b(v.y - b2f(h.y));
    h.z = f2b(v.z); l.z = f2b(v.z - b2f(h.z));
    h.w = f2b(v.w); l.w = f2b(v.w - b2f(h.w));
    ((ushort4*)hi)[i] = h;
    ((ushort4*)lo)[i] = l;
  }
}

// ---- Weff[h*64+k][e] = sum_d s4*sigma[h,d]*rm[h,k,d]*W[h*128+d][e]; beff likewise from b.
__global__ __launch_bounds__(256) void weff_kernel(
    const float* __restrict__ rmat, const float* __restrict__ sigma,
    const float* __restrict__ W, const float* __restrict__ bvec,
    float* __restrict__ Weff, float* __restrict__ beff)
{
  __shared__ float rme[64][130];
  __shared__ float Wt[128][130];
  const int et = blockIdx.x;
  const int h  = blockIdx.y;
  const int tid = threadIdx.x;
  const int e0 = et * 128;
  const float s4 = 0.29730177875068026f;  // 128^-0.25

  for (int f = tid; f < 64 * 32; f += 256) {
    int kk = f >> 5, d = (f & 31) * 4;
    float4 rv = *(const float4*)(rmat + ((size_t)(h * 64 + kk)) * 128 + d);
    const float* sg = sigma + h * 128 + d;
    rme[kk][d + 0] = rv.x * sg[0] * s4;
    rme[kk][d + 1] = rv.y * sg[1] * s4;
    rme[kk][d + 2] = rv.z * sg[2] * s4;
    rme[kk][d + 3] = rv.w * sg[3] * s4;
  }
  for (int f = tid; f < 128 * 32; f += 256) {
    int dd = f >> 5, e = (f & 31) * 4;
    *(float4*)&Wt[dd][e] = *(const float4*)(W + ((size_t)(h * 128 + dd)) * EE + e0 + e);
  }
  __syncthreads();
  const int nl = tid >> 2;
  const int el0 = (tid & 3) * 32;
  for (int e = 0; e < 32; ++e) {
    float acc = 0.f;
#pragma unroll
    for (int d = 0; d < 128; ++d)
      acc = fmaf(rme[nl][d], Wt[d][el0 + e], acc);
    Weff[(size_t)(h * 64 + nl) * EE + e0 + el0 + e] = acc;
  }
  if (et == 0 && tid < 64) {
    float acc = 0.f;
    for (int d = 0; d < 128; ++d)
      acc = fmaf(rme[tid][d], bvec[h * 128 + d], acc);
    beff[h * 64 + tid] = acc;
  }
}

// ---------------- MFMA GEMM: C[M,N] = A[M,K] @ W[N,K]^T + bias[N]
// fp32 split compensation fused in one K-loop:
//   NPASS=3: acc += Ahi*Whi + Ahi*Wlo + Alo*Whi ; NPASS=2: acc += Ahi*Whi + Ahi*Wlo
// m97 structure: 128x128 tile, BK=32, 4 waves (2x2), 4x4 16x16x32 frags/wave.
template<int OUTBF16, int NPASS>
__global__ __launch_bounds__(256) void gemm_mfma(
    const unsigned short* __restrict__ Ahi, const unsigned short* __restrict__ Alo,
    const unsigned short* __restrict__ Whi, const unsigned short* __restrict__ Wlo,
    const float* __restrict__ bias, void* __restrict__ Cout, int M, int N, int Kd)
{
  __shared__ __align__(16) unsigned short Ahs[128 * 32];
  __shared__ __align__(16) unsigned short Whs[128 * 32];
  __shared__ __align__(16) unsigned short Wls[128 * 32];
  __shared__ __align__(16) unsigned short Als[128 * 32];
  const int tid = threadIdx.x;
  const int w = tid >> 6, l = tid & 63;
  const int m0 = blockIdx.x * 128, n0 = blockIdx.y * 128;
  const int wm = (w >> 1) * 64, wn = (w & 1) * 64;
  const int rowA = tid >> 2, ko = (tid & 3) * 8;

  f32x4 acc[4][4] = {};
  const int sb0 = w * 512, sb1 = 2048 + w * 512;
  const int fA = (wm + (l & 15)) * 32 + (l >> 4) * 8;
  const int fW = (wn + (l & 15)) * 32 + (l >> 4) * 8;

  const unsigned short* gah0 = Ahi + (size_t)(m0 + rowA) * Kd + ko;
  const unsigned short* gah1 = Ahi + (size_t)(m0 + 64 + rowA) * Kd + ko;
  const unsigned short* gwh0 = Whi + (size_t)(n0 + rowA) * Kd + ko;
  const unsigned short* gwh1 = Whi + (size_t)(n0 + 64 + rowA) * Kd + ko;
  const unsigned short* gwl0 = Wlo + (size_t)(n0 + rowA) * Kd + ko;
  const unsigned short* gwl1 = Wlo + (size_t)(n0 + 64 + rowA) * Kd + ko;
  const unsigned short* gal0 = nullptr;
  const unsigned short* gal1 = nullptr;
  if (NPASS == 3) {
    gal0 = Alo + (size_t)(m0 + rowA) * Kd + ko;
    gal1 = Alo + (size_t)(m0 + 64 + rowA) * Kd + ko;
  }

#pragma unroll 1
  for (int kt = 0; kt < Kd; kt += 32) {
    __syncthreads();
    stage16(gah0 + kt, Ahs + sb0);
    stage16(gah1 + kt, Ahs + sb1);
    stage16(gwh0 + kt, Whs + sb0);
    stage16(gwh1 + kt, Whs + sb1);
    stage16(gwl0 + kt, Wls + sb0);
    stage16(gwl1 + kt, Wls + sb1);
    if (NPASS == 3) {
      stage16(gal0 + kt, Als + sb0);
      stage16(gal1 + kt, Als + sb1);
    }
    __syncthreads();
    bf16x8 ah[4], wh[4], wl[4];
#pragma unroll
    for (int i = 0; i < 4; ++i) {
      ah[i] = ldfrag(Ahs + fA + i * 512);
      wh[i] = ldfrag(Whs + fW + i * 512);
      wl[i] = ldfrag(Wls + fW + i * 512);
    }
#pragma unroll
    for (int i = 0; i < 4; ++i)
#pragma unroll
      for (int j = 0; j < 4; ++j)
        acc[i][j] = __builtin_amdgcn_mfma_f32_16x16x32_bf16(ah[i], wh[j], acc[i][j], 0, 0, 0);
#pragma unroll
    for (int i = 0; i < 4; ++i)
#pragma unroll
      for (int j = 0; j < 4; ++j)
        acc[i][j] = __builtin_amdgcn_mfma_f32_16x16x32_bf16(ah[i], wl[j], acc[i][j], 0, 0, 0);
    if (NPASS == 3) {
      bf16x8 al[4];
#pragma unroll
      for (int i = 0; i < 4; ++i) al[i] = ldfrag(Als + fA + i * 512);
#pragma unroll
      for (int i = 0; i < 4; ++i)
#pragma unroll
        for (int j = 0; j < 4; ++j)
          acc[i][j] = __builtin_amdgcn_mfma_f32_16x16x32_bf16(al[i], wh[j], acc[i][j], 0, 0, 0);
    }
  }

  const int cl = l & 15, rg = (l >> 4) * 4;
  float bvv[4];
#pragma unroll
  for (int j = 0; j < 4; ++j) bvv[j] = bias[n0 + wn + j * 16 + cl];
#pragma unroll
  for (int i = 0; i < 4; ++i) {
    const int row = m0 + wm + i * 16 + rg;
#pragma unroll
    for (int r = 0; r < 4; ++r) {
#pragma unroll
      for (int j = 0; j < 4; ++j) {
        float v = acc[i][j][r] + bvv[j];
        if (OUTBF16) {
          ((unsigned short*)Cout)[(size_t)(row + r) * N + n0 + wn + j * 16 + cl] = f2b(v);
        } else {
          ((float*)Cout)[(size_t)(row + r) * N + n0 + wn + j * 16 + cl] = v;
        }
      }
    }
  }
}

// ---------------- phicast: P [NROWS][512] fp32 -> Phi [NROWS][1024] bf16
// Phi[row][h*128 + k] = sin(p)*.125 ; [h*128 + 64 + k] = cos(p)*.125
__global__ __launch_bounds__(256) void phicast_kernel(
    const float* __restrict__ P, unsigned short* __restrict__ Phi)
{
  const int n4 = NROWS * NPROJ / 4;
  int stride = gridDim.x * 256;
  for (int i = blockIdx.x * 256 + threadIdx.x; i < n4; i += stride) {
    float4 p = ((const float4*)P)[i];
    int i4 = i * 4;
    int row = i4 >> 9, c = i4 & 511;
    int h = c >> 6, k = c & 63;
    unsigned short* op = Phi + (size_t)row * EE + h * PHI2 + k;
    float sv, cv;
    ushort4 so, co;
    sincosf(p.x, &sv, &cv); so.x = f2b(sv * 0.125f); co.x = f2b(cv * 0.125f);
    sincosf(p.y, &sv, &cv); so.y = f2b(sv * 0.125f); co.y = f2b(cv * 0.125f);
    sincosf(p.z, &sv, &cv); so.z = f2b(sv * 0.125f); co.z = f2b(cv * 0.125f);
    sincosf(p.w, &sv, &cv); so.w = f2b(sv * 0.125f); co.w = f2b(cv * 0.125f);
    *(ushort4*)op = so;
    *(ushort4*)(op + 64) = co;
  }
}

// ---------------- Vb [t*8+b][h*128+d] -> VbT [(b*8+h)*128+d][t]
__global__ __launch_bounds__(256) void vtrans_kernel(
    const unsigned short* __restrict__ Vb, unsigned short* __restrict__ VbT)
{
  __shared__ __align__(16) unsigned short T[128 * 132];
  const int tt = blockIdx.x, b = blockIdx.y, h = blockIdx.z;
  const int tid = threadIdx.x;
  {
    int t = tid >> 1, f0 = (tid & 1) * 64;
    const unsigned short* gp = Vb + ((size_t)((tt * 128 + t) * BB + b)) * EE + h * DD + f0;
    unsigned short* lp = T + t * 132 + f0;
#pragma unroll
    for (int k8 = 0; k8 < 8; ++k8) {
      u16x8 v = *(const u16x8*)(gp + k8 * 8);
      u16x4 vl = __builtin_shufflevector(v, v, 0, 1, 2, 3);
      u16x4 vh = __builtin_shufflevector(v, v, 4, 5, 6, 7);
      *(u16x4*)(lp + k8 * 8) = vl;
      *(u16x4*)(lp + k8 * 8 + 4) = vh;
    }
  }
  __syncthreads();
  const size_t obase = ((size_t)(b * HH + h) * DD) * 4096 + tt * 128;
#pragma unroll
  for (int dd = 0; dd < 4; ++dd) {
    int d = (tid >> 3) + dd * 32;
    int t0 = (tid & 7) * 16;
    u16x8 o0, o1;
#pragma unroll
    for (int e = 0; e < 8; ++e) {
      o0[e] = T[(t0 + e) * 132 + d];
      o1[e] = T[(t0 + 8 + e) * 132 + d];
    }
    *(u16x8*)(VbT + obase + (size_t)d * 4096 + t0) = o0;
    *(u16x8*)(VbT + obase + (size_t)d * 4096 + t0 + 8) = o1;
  }
}

// ---------------- den1: Z1[(bh*NC+c)*128 + f] = sum_{j in chunk} phik[j][f]  (fp32)
__global__ __launch_bounds__(256) void den1_kernel(
    const float* __restrict__ Pk, float* __restrict__ Z1)
{
  __shared__ float red[4][130];
  const int c = blockIdx.x, b = blockIdx.y, h = blockIdx.z;
  const int tid = threadIdx.x;
  const int k = tid & 63, part = tid >> 6;
  float ss = 0.f, cs = 0.f;
  const float* pb = Pk + ((size_t)(c * CH) * BB + b) * NPROJ + h * KK + k;
  for (int j = part * 32; j < part * 32 + 32; ++j) {
    float p = pb[(size_t)j * BB * NPROJ];
    float sv, cv; sincosf(p, &sv, &cv);
    ss += sv; cs += cv;
  }
  red[part][k] = ss * 0.125f;
  red[part][k + 65] = cs * 0.125f;
  __syncthreads();
  if (tid < 128) {
    int f = tid;
    int idx = (f < 64) ? f : (f + 1);
    float s = red[0][idx] + red[1][idx] + red[2][idx] + red[3][idx];
    Z1[((size_t)(b * HH + h) * NC + c) * 128 + f] = s;
  }
}

// ---------------- zscan: exclusive prefix of Z1 over chunks, per (bh, f)
__global__ __launch_bounds__(256) void zscan_kernel(float* __restrict__ Z1)
{
  int gid = blockIdx.x * 256 + threadIdx.x;
  if (gid >= 64 * 128) return;
  int bh = gid >> 7, f = gid & 127;
  float* p = Z1 + (size_t)bh * NC * 128 + f;
  float run = 0.f;
#pragma unroll
  for (int cc = 0; cc < NC; ++cc) {
    float t = p[cc * 128];
    p[cc * 128] = run;
    run += t;
  }
}

// ---------------- den2: Den[bh*TT + c*128 + row] = phiq[row] . (Z1_prefix + cumsum_{j<=row} phik[j])
__global__ __launch_bounds__(256) void den2_kernel(
    const float* __restrict__ Pq, const float* __restrict__ Pk,
    const float* __restrict__ Z1, float* __restrict__ Den)
{
  __shared__ float Ks[128][132];
  const int c = blockIdx.x, b = blockIdx.y, h = blockIdx.z;
  const int tid = threadIdx.x;
  const int bh = b * HH + h;
  {  // phase 1: Ks[j][f] = phik[j][f]
    int j = tid >> 1, k0 = (tid & 1) * 32;
    const float* pp = Pk + ((size_t)(c * CH + j) * BB + b) * NPROJ + h * KK + k0;
#pragma unroll
    for (int k4 = 0; k4 < 32; k4 += 4) {
      float4 p = *(const float4*)(pp + k4);
      float sv, cv;
      sincosf(p.x, &sv, &cv); Ks[j][k0 + k4 + 0] = sv * 0.125f; Ks[j][64 + k0 + k4 + 0] = cv * 0.125f;
      sincosf(p.y, &sv, &cv); Ks[j][k0 + k4 + 1] = sv * 0.125f; Ks[j][64 + k0 + k4 + 1] = cv * 0.125f;
      sincosf(p.z, &sv, &cv); Ks[j][k0 + k4 + 2] = sv * 0.125f; Ks[j][64 + k0 + k4 + 2] = cv * 0.125f;
      sincosf(p.w, &sv, &cv); Ks[j][k0 + k4 + 3] = sv * 0.125f; Ks[j][64 + k0 + k4 + 3] = cv * 0.125f;
    }
  }
  __syncthreads();
  if (tid < 128) {  // phase 2: inclusive cumsum down j, seeded with exclusive chunk prefix
    int f = tid;
    float run = Z1[((size_t)bh * NC + c) * 128 + f];
    for (int j = 0; j < 128; ++j) { run += Ks[j][f]; Ks[j][f] = run; }
  }
  __syncthreads();
  {  // phase 3: den[row] = sum_f phiq[row][f] * Ks[row][f]
    int row = tid >> 1, half = tid & 1;
    const float* pq = Pq + ((size_t)(c * CH + row) * BB + b) * NPROJ + h * KK;
    float acc = 0.f;
#pragma unroll 4
    for (int k = 0; k < 64; ++k) {
      float sv, cv; sincosf(pq[k], &sv, &cv);
      float phi = (half ? cv : sv) * 0.125f;
      acc = fmaf(phi, Ks[row][half * 64 + k], acc);
    }
    acc += __shfl_xor(acc, 1);
    if (half == 0) Den[(size_t)bh * TT + c * CH + row] = acc;
  }
}

// ---------------- pass1 (MFMA): St_c[d][f] = sum_j VbT[d][j]*phik[j][f]
__global__ __launch_bounds__(256) void pass1_mfma(
    const unsigned short* __restrict__ Phk, const unsigned short* __restrict__ VbT,
    unsigned short* __restrict__ St)
{
  __shared__ __align__(16) unsigned short KT[128 * 132];  // [f][j]
  __shared__ __align__(16) unsigned short Am[128 * 40];   // [d][32 j] stream
  const int c = blockIdx.x, b = blockIdx.y, h = blockIdx.z;
  const int tid = threadIdx.x;
  const int w = tid >> 6, l = tid & 63;
  const int wm = (w >> 1) * 64, wn = (w & 1) * 64;
  const int cl = l & 15, ks = l >> 4;
  const int bh = b * HH + h;

  {  // transpose-stage phi_k tile into KT[f][j]
    int j = tid >> 1, f0 = (tid & 1) * 64;
    const unsigned short* gp = Phk + ((size_t)(c * CH + j) * BB + b) * EE + h * PHI2 + f0;
#pragma unroll
    for (int k8 = 0; k8 < 8; ++k8) {
      u16x8 v = *(const u16x8*)(gp + k8 * 8);
#pragma unroll
      for (int e = 0; e < 8; ++e) KT[(f0 + k8 * 8 + e) * 132 + j] = v[e];
    }
  }

  f32x4 acc[4][4] = {};
  const unsigned short* vbase = VbT + (size_t)bh * DD * 4096 + c * CH;
#pragma unroll 1
  for (int j0 = 0; j0 < 128; j0 += 32) {
    __syncthreads();
    stage_rs(vbase + j0, 4096, Am, tid);
    __syncthreads();
    bf16x8 af[4], wf[4];
#pragma unroll
    for (int i = 0; i < 4; ++i) {
      af[i] = ldfrag(Am + (wm + cl + i * 16) * 40 + ks * 8);
      wf[i] = ldfrag64(KT + (wn + cl + i * 16) * 132 + j0 + ks * 8);
    }
#pragma unroll
    for (int i = 0; i < 4; ++i)
#pragma unroll
      for (int j = 0; j < 4; ++j)
        acc[i][j] = __builtin_amdgcn_mfma_f32_16x16x32_bf16(af[i], wf[j], acc[i][j], 0, 0, 0);
  }
  unsigned short* sp = St + (size_t)(bh * NC + c) * (DD * PHI2);
#pragma unroll
  for (int i = 0; i < 4; ++i) {
    int d = wm + i * 16 + ks * 4;
#pragma unroll
    for (int r = 0; r < 4; ++r) {
#pragma unroll
      for (int j = 0; j < 4; ++j)
        sp[(size_t)(d + r) * PHI2 + wn + j * 16 + cl] = f2b(acc[i][j][r]);
    }
  }
}

// ---------------- sscan: exclusive prefix over chunks of St (bf16, fp32 carry)
__global__ __launch_bounds__(256) void sscan_kernel(unsigned short* __restrict__ Sb)
{
  int gid = blockIdx.x * 256 + threadIdx.x;
  if (gid >= 64 * CH * DD) return;
  int bh = gid >> 14, fd = gid & 16383;
  unsigned short* p = Sb + (size_t)bh * NC * 16384 + fd;
  float run = 0.f;
#pragma unroll
  for (int cc = 0; cc < NC; ++cc) {
    float t = b2f(p[(size_t)cc * 16384]);
    p[(size_t)cc * 16384] = f2b(run);
    run += t;
  }
}

// ---------------- attn (MFMA): per (c,b,h)
// sc = phiq @ phik^T (causal); num = sc @ VbT^T + phiq @ St^T; Ob = num / max(Den, eps)
__global__ __launch_bounds__(256) void attn_mfma(
    const unsigned short* __restrict__ Phq, const unsigned short* __restrict__ Phk,
    const unsigned short* __restrict__ VbT, const unsigned short* __restrict__ St,
    const float* __restrict__ Den, unsigned short* __restrict__ Ob)
{
  __shared__ __align__(16) unsigned short Qs[128 * 132];
  __shared__ __align__(16) unsigned short sc[128 * 132];
  __shared__ __align__(16) unsigned short Sm[128 * 40];
  __shared__ float den_s[128];
  const int c = blockIdx.x, b = blockIdx.y, h = blockIdx.z;
  const int tid = threadIdx.x;
  const int w = tid >> 6, l = tid & 63;
  const int wm = (w >> 1) * 64, wn = (w & 1) * 64;
  const int cl = l & 15, ks = l >> 4;
  const int bh = b * HH + h;

  {  // stage phi_q tile
    int r = tid >> 1, f0 = (tid & 1) * 64;
    const unsigned short* gp = Phq + ((size_t)(c * CH + r) * BB + b) * EE + h * PHI2 + f0;
    unsigned short* lp = Qs + r * 132 + f0;
#pragma unroll
    for (int k8 = 0; k8 < 8; ++k8) {
      u16x8 v = *(const u16x8*)(gp + k8 * 8);
      u16x4 vl = __builtin_shufflevector(v, v, 0, 1, 2, 3);
      u16x4 vh = __builtin_shufflevector(v, v, 4, 5, 6, 7);
      *(u16x4*)(lp + k8 * 8) = vl;
      *(u16x4*)(lp + k8 * 8 + 4) = vh;
    }
  }
  if (tid < 128) den_s[tid] = Den[(size_t)bh * TT + c * CH + tid];

  f32x4 acc[4][4] = {};
  // ---- phase A: scores
  const unsigned short* kbase = Phk + ((size_t)(c * CH) * BB + b) * EE + h * PHI2;
#pragma unroll 1
  for (int ft = 0; ft < PHI2; ft += 32) {
    __syncthreads();
    stage_rs(kbase + ft, (size_t)BB * EE, Sm, tid);
    __syncthreads();
    if (w != 1) {  // wave (rows 0-63, cols 64-127) fully masked -> skip
      bf16x8 af[4], wf[4];
#pragma unroll
      for (int i = 0; i < 4; ++i) {
        af[i] = ldfrag64(Qs + (wm + cl + i * 16) * 132 + ft + ks * 8);
        wf[i] = ldfrag(Sm + (wn + cl + i * 16) * 40 + ks * 8);
      }
#pragma unroll
      for (int i = 0; i < 4; ++i)
#pragma unroll
        for (int j = 0; j < 4; ++j)
          acc[i][j] = __builtin_amdgcn_mfma_f32_16x16x32_bf16(af[i], wf[j], acc[i][j], 0, 0, 0);
    }
  }
  __syncthreads();
#pragma unroll
  for (int i = 0; i < 4; ++i) {
    int row0 = wm + i * 16 + ks * 4;
#pragma unroll
    for (int r = 0; r < 4; ++r) {
      int row = row0 + r;
#pragma unroll
      for (int j = 0; j < 4; ++j) {
        int col = wn + j * 16 + cl;
        sc[row * 132 + col] = f2b((col <= row) ? acc[i][j][r] : 0.f);
      }
    }
  }
  __syncthreads();

  // ---- phase B
#pragma unroll
  for (int i = 0; i < 4; ++i)
#pragma unroll
    for (int j = 0; j < 4; ++j) acc[i][j] = (f32x4){0.f, 0.f, 0.f, 0.f};

  const unsigned short* vbase = VbT + (size_t)bh * DD * 4096 + c * CH;
#pragma unroll 1
  for (int j0 = 0; j0 < 128; j0 += 32) {
    __syncthreads();
    stage_rs(vbase + j0, 4096, Sm, tid);
    __syncthreads();
    if (!(wm == 0 && j0 >= 64)) {
      bf16x8 af[4], wf[4];
#pragma unroll
      for (int i = 0; i < 4; ++i) {
        af[i] = ldfrag64(sc + (wm + cl + i * 16) * 132 + j0 + ks * 8);
        wf[i] = ldfrag(Sm + (wn + cl + i * 16) * 40 + ks * 8);
      }
#pragma unroll
      for (int i = 0; i < 4; ++i)
#pragma unroll
        for (int j = 0; j < 4; ++j)
          acc[i][j] = __builtin_amdgcn_mfma_f32_16x16x32_bf16(af[i], wf[j], acc[i][j], 0, 0, 0);
    }
  }
  const unsigned short* sbase = St + (size_t)(bh * NC + c) * (DD * PHI2);
#pragma unroll 1
  for (int f0 = 0; f0 < PHI2; f0 += 32) {
    __syncthreads();
    stage_rs(sbase + f0, PHI2, Sm, tid);
    __syncthreads();
    bf16x8 af[4], wf[4];
#pragma unroll
    for (int i = 0; i < 4; ++i) {
      af[i] = ldfrag64(Qs + (wm + cl + i * 16) * 132 + f0 + ks * 8);
      wf[i] = ldfrag(Sm + (wn + cl + i * 16) * 40 + ks * 8);
    }
#pragma unroll
    for (int i = 0; i < 4; ++i)
#pragma unroll
      for (int j = 0; j < 4; ++j)
        acc[i][j] = __builtin_amdgcn_mfma_f32_16x16x32_bf16(af[i], wf[j], acc[i][j], 0, 0, 0);
  }
#pragma unroll
  for (int i = 0; i < 4; ++i) {
    int row0 = wm + i * 16 + ks * 4;
#pragma unroll
    for (int r = 0; r < 4; ++r) {
      int row = row0 + r;
      float inv = 1.0f / fmaxf(den_s[row], EPSV);
      unsigned short* op = Ob + ((size_t)(c * CH + row) * BB + b) * EE + h * DD;
#pragma unroll
      for (int j = 0; j < 4; ++j)
        op[wn + j * 16 + cl] = f2b(acc[i][j][r] * inv);
    }
  }
}

extern "C" void kernel_launch(void* const* d_in, const int* in_sizes, int n_in,
                              void* d_out, int out_size, void* d_ws, size_t ws_size,
                              hipStream_t stream)
{
  const float* x     = (const float*)d_in[0];
  const float* rmat  = (const float*)d_in[1];
  const float* Wq    = (const float*)d_in[2];
  const float* bq    = (const float*)d_in[3];
  const float* Wk    = (const float*)d_in[4];
  const float* bk    = (const float*)d_in[5];
  const float* Wv    = (const float*)d_in[6];
  const float* bv    = (const float*)d_in[7];
  const float* Wo    = (const float*)d_in[8];
  const float* bo    = (const float*)d_in[9];
  const float* sigma = (const float*)d_in[10];

  // ---- workspace (256 MiB), lifetimes stream-ordered:
  //   [0,  64Mi): pq_p fp32 (steps 4-11) -> St bf16 (pass1 out, steps 12-14)
  //   [64,128Mi): pk_p fp32 (steps 5-11) -> Ob bf16 (attn out, steps 14-16)
  //   [128,192Mi): Vb bf16 (steps 6-8) -> Z1 fp32 @128Mi, Den fp32 @129Mi, Woh @130Mi, Wol @132Mi
  //   [192,256Mi): Weff/biases/weight-splits (steps 2-6) -> VbT bf16 (vtrans out, steps 8-14)
  // ---- d_out (128 MiB):
  //   xhi [0,64Mi), xlo [64,128Mi) (steps 1-6) -> Phq [0,64Mi), Phk [64,128Mi) (steps 7-14)
  //   -> final fp32 output (step 16)
  char* wsb = (char*)d_ws;
  float* pq_p = (float*)wsb;
  float* pk_p = (float*)(wsb + (64LL << 20));
  unsigned short* Stb = (unsigned short*)wsb;
  unsigned short* Ob  = (unsigned short*)(wsb + (64LL << 20));
  unsigned short* Vb  = (unsigned short*)(wsb + (128LL << 20));
  float* Z1  = (float*)(wsb + (128LL << 20));
  float* Den = (float*)(wsb + (129LL << 20));
  unsigned short* Woh = (unsigned short*)(wsb + (130LL << 20));
  unsigned short* Wol = (unsigned short*)(wsb + (132LL << 20));
  unsigned short* VbT = (unsigned short*)(wsb + (192LL << 20));
  float* Weq = (float*)(wsb + (192LL << 20));
  float* Wek = (float*)(wsb + (194LL << 20));
  float* beq = (float*)(wsb + (196LL << 20));
  float* bek = (float*)(wsb + (196LL << 20) + 65536);
  unsigned short* Weqh = (unsigned short*)(wsb + (197LL << 20));
  unsigned short* Weql = (unsigned short*)(wsb + (198LL << 20));
  unsigned short* Wekh = (unsigned short*)(wsb + (199LL << 20));
  unsigned short* Wekl = (unsigned short*)(wsb + (200LL << 20));
  unsigned short* Wvh  = (unsigned short*)(wsb + (201LL << 20));
  unsigned short* Wvl  = (unsigned short*)(wsb + (203LL << 20));

  char* ob = (char*)d_out;
  unsigned short* xhi = (unsigned short*)ob;
  unsigned short* xlo = (unsigned short*)(ob + (64LL << 20));
  unsigned short* Phq = (unsigned short*)ob;
  unsigned short* Phk = (unsigned short*)(ob + (64LL << 20));

  dim3 bt(256);
  // 1-3: casts + effective projection weights + splits
  hipLaunchKernelGGL(split_kernel, dim3(2048), bt, 0, stream, x, xhi, xlo, NROWS * EE / 4);
  hipLaunchKernelGGL(weff_kernel, dim3(8, 8), bt, 0, stream, rmat, sigma, Wq, bq, Weq, beq);
  hipLaunchKernelGGL(weff_kernel, dim3(8, 8), bt, 0, stream, rmat, sigma, Wk, bk, Wek, bek);
  hipLaunchKernelGGL(split_kernel, dim3(512), bt, 0, stream, Weq, Weqh, Weql, NPROJ * EE / 4);
  hipLaunchKernelGGL(split_kernel, dim3(512), bt, 0, stream, Wek, Wekh, Wekl, NPROJ * EE / 4);
  hipLaunchKernelGGL(split_kernel, dim3(1024), bt, 0, stream, Wv, Wvh, Wvl, EE * EE / 4);
  // 4-6: projections (fp32 p for q/k; bf16 V)
  hipLaunchKernelGGL((gemm_mfma<0, 3>), dim3(NROWS / 128, NPROJ / 128), bt, 0, stream,
                     xhi, xlo, Weqh, Weql, beq, (void*)pq_p, NROWS, NPROJ, EE);
  hipLaunchKernelGGL((gemm_mfma<0, 3>), dim3(NROWS / 128, NPROJ / 128), bt, 0, stream,
                     xhi, xlo, Wekh, Wekl, bek, (void*)pk_p, NROWS, NPROJ, EE);
  hipLaunchKernelGGL((gemm_mfma<1, 3>), dim3(NROWS / 128, EE / 128), bt, 0, stream,
                     xhi, xlo, Wvh, Wvl, bv, (void*)Vb, NROWS, EE, EE);
  // 7: bf16 phi buffers (xhi/xlo dead)
  hipLaunchKernelGGL(phicast_kernel, dim3(2048), bt, 0, stream, pq_p, Phq);
  hipLaunchKernelGGL(phicast_kernel, dim3(2048), bt, 0, stream, pk_p, Phk);
  // 8: V transpose (weights dead)
  hipLaunchKernelGGL(vtrans_kernel, dim3(NC, BB, HH), bt, 0, stream, Vb, VbT);
  // 9-11: fp32 denominator path (Vb dead)
  hipLaunchKernelGGL(den1_kernel, dim3(NC, BB, HH), bt, 0, stream, pk_p, Z1);
  hipLaunchKernelGGL(zscan_kernel, dim3(32), bt, 0, stream, Z1);
  hipLaunchKernelGGL(den2_kernel, dim3(NC, BB, HH), bt, 0, stream, pq_p, pk_p, Z1, Den);
  // 12-13: chunk states + exclusive scan (pq_p dead -> St)
  hipLaunchKernelGGL(pass1_mfma, dim3(NC, BB, HH), bt, 0, stream, Phk, VbT, Stb);
  hipLaunchKernelGGL(sscan_kernel, dim3(4096), bt, 0, stream, Stb);
  // 14: attention (pk_p dead -> Ob)
  hipLaunchKernelGGL(attn_mfma, dim3(NC, BB, HH), bt, 0, stream, Phq, Phk, VbT, Stb, Den, Ob);
  // 15-16: output projection
  hipLaunchKernelGGL(split_kernel, dim3(1024), bt, 0, stream, Wo, Woh, Wol, EE * EE / 4);
  hipLaunchKernelGGL((gemm_mfma<0, 2>), dim3(NROWS / 128, EE / 128), bt, 0, stream,
                     Ob, (const unsigned short*)0, Woh, Wol, bo, (void*)d_out, NROWS, EE, EE);
}

// Round 5
// 1334.030 us; speedup vs baseline: 2.7226x; 1.0270x over previous
//
#include <hip/hip_runtime.h>
#include <math.h>

#define TT 4096
#define BB 8
#define EE 1024
#define HH 8
#define DD 128
#define KK 64        // proj dim per head
#define PHI2 128     // 2K features per head
#define NPROJ 512    // H*K total pre-sincos width
#define CH 128
#define NC 32
#define NROWS 32768
#define EPSV 1e-6f

typedef float f32x4 __attribute__((ext_vector_type(4)));
typedef __bf16 bf16x8 __attribute__((ext_vector_type(8)));
typedef unsigned short u16x8 __attribute__((ext_vector_type(8)));
typedef unsigned short u16x4 __attribute__((ext_vector_type(4)));

__device__ __forceinline__ unsigned short f2b(float f) {
  union { float f; unsigned int u; } v; v.f = f;
  unsigned int u = v.u;
  u += 0x7fffu + ((u >> 16) & 1u);
  return (unsigned short)(u >> 16);
}
__device__ __forceinline__ float b2f(unsigned short h) {
  union { float f; unsigned int u; } v; v.u = ((unsigned int)h) << 16;
  return v.f;
}

// async global->LDS, 16B per lane; lds ptr must be wave-uniform (HW writes base+lane*16).
__device__ __forceinline__ void stage16(const void* g, void* l) {
  __builtin_amdgcn_global_load_lds(
      (const __attribute__((address_space(1))) void*)g,
      (__attribute__((address_space(3))) void*)l, 16, 0, 0);
}

__device__ __forceinline__ bf16x8 ldfrag(const unsigned short* p) {  // 16B-aligned
  u16x8 s = *(const u16x8*)p;
  return __builtin_bit_cast(bf16x8, s);
}
__device__ __forceinline__ bf16x8 ldfrag64(const unsigned short* p) {  // 8B-aligned (pitch-132 LDS)
  u16x4 a = *(const u16x4*)p;
  u16x4 b = *(const u16x4*)(p + 4);
  u16x8 v = {a[0], a[1], a[2], a[3], b[0], b[1], b[2], b[3]};
  return __builtin_bit_cast(bf16x8, v);
}

// stream-stage [128 rows][32 cols] bf16 from global (row stride rstride shorts)
// into LDS pitch 40 (80B rows, 16B-aligned). all 256 threads.
__device__ __forceinline__ void stage_rs(const unsigned short* gbase, size_t rstride,
                                         unsigned short* lds, int tid)
{
  int r = tid >> 1, c0 = (tid & 1) * 16;
  const unsigned short* gp = gbase + (size_t)r * rstride + c0;
  u16x8 v0 = *(const u16x8*)gp;
  u16x8 v1 = *(const u16x8*)(gp + 8);
  *(u16x8*)(lds + r * 40 + c0) = v0;
  *(u16x8*)(lds + r * 40 + c0 + 8) = v1;
}

// ---- split fp32 -> bf16 hi + bf16 lo (residual), vectorized x4
__global__ __launch_bounds__(256) void split_kernel(
    const float* __restrict__ in, unsigned short* __restrict__ hi,
    unsigned short* __restrict__ lo, int n4)
{
  int stride = gridDim.x * 256;
  for (int i = blockIdx.x * 256 + threadIdx.x; i < n4; i += stride) {
    float4 v = ((const float4*)in)[i];
    ushort4 h, l;
    h.x = f2b(v.x); l.x = f2b(v.x - b2f(h.x));
    h.y = f2b(v.y); l.y = f2b(v.y - b2f(h.y));
    h.z = f2b(v.z); l.z = f2b(v.z - b2f(h.z));
    h.w = f2b(v.w); l.w = f2b(v.w - b2f(h.w));
    ((ushort4*)hi)[i] = h;
    ((ushort4*)lo)[i] = l;
  }
}

// ---- Weff[h*64+k][e] = sum_d s4*sigma[h,d]*rm[h,k,d]*W[h*128+d][e]; beff likewise from b.
__global__ __launch_bounds__(256) void weff_kernel(
    const float* __restrict__ rmat, const float* __restrict__ sigma,
    const float* __restrict__ W, const float* __restrict__ bvec,
    float* __restrict__ Weff, float* __restrict__ beff)
{
  __shared__ float rme[64][130];
  __shared__ float Wt[128][130];
  const int et = blockIdx.x;
  const int h  = blockIdx.y;
  const int tid = threadIdx.x;
  const int e0 = et * 128;
  const float s4 = 0.29730177875068026f;  // 128^-0.25

  for (int f = tid; f < 64 * 32; f += 256) {
    int kk = f >> 5, d = (f & 31) * 4;
    float4 rv = *(const float4*)(rmat + ((size_t)(h * 64 + kk)) * 128 + d);
    const float* sg = sigma + h * 128 + d;
    rme[kk][d + 0] = rv.x * sg[0] * s4;
    rme[kk][d + 1] = rv.y * sg[1] * s4;
    rme[kk][d + 2] = rv.z * sg[2] * s4;
    rme[kk][d + 3] = rv.w * sg[3] * s4;
  }
  for (int f = tid; f < 128 * 32; f += 256) {
    int dd = f >> 5, e = (f & 31) * 4;
    *(float4*)&Wt[dd][e] = *(const float4*)(W + ((size_t)(h * 128 + dd)) * EE + e0 + e);
  }
  __syncthreads();
  const int nl = tid >> 2;
  const int el0 = (tid & 3) * 32;
  for (int e = 0; e < 32; ++e) {
    float acc = 0.f;
#pragma unroll
    for (int d = 0; d < 128; ++d)
      acc = fmaf(rme[nl][d], Wt[d][el0 + e], acc);
    Weff[(size_t)(h * 64 + nl) * EE + e0 + el0 + e] = acc;
  }
  if (et == 0 && tid < 64) {
    float acc = 0.f;
    for (int d = 0; d < 128; ++d)
      acc = fmaf(rme[tid][d], bvec[h * 128 + d], acc);
    beff[h * 64 + tid] = acc;
  }
}

// ---------------- MFMA GEMM: C[M,N] = A[M,K] @ W[N,K]^T + bias[N]
// fp32 split compensation fused in one K-loop:
//   NPASS=3: acc += Ahi*Whi + Ahi*Wlo + Alo*Whi ; NPASS=2: acc += Ahi*(Whi + Wlo)
// m97 structure: 128x128 tile, BK=32, 4 waves (2x2), 4x4 16x16x32 frags/wave.
// Grid is XCD-swizzled (bijective; requires gridDim.x % 8 == 0).
template<int OUTBF16, int NPASS>
__global__ __launch_bounds__(256) void gemm_mfma(
    const unsigned short* __restrict__ Ahi, const unsigned short* __restrict__ Alo,
    const unsigned short* __restrict__ Whi, const unsigned short* __restrict__ Wlo,
    const float* __restrict__ bias, void* __restrict__ Cout, int M, int N, int Kd)
{
  __shared__ __align__(16) unsigned short Ahs[128 * 32];
  __shared__ __align__(16) unsigned short Whs[128 * 32];
  __shared__ __align__(16) unsigned short Wls[128 * 32];
  __shared__ __align__(16) unsigned short Als[NPASS == 3 ? 128 * 32 : 8];
  const int tid = threadIdx.x;
  const int w = tid >> 6, l = tid & 63;
  // XCD-aware bijective swizzle: same-M-tile blocks adjacent on one XCD.
  int bx, by;
  {
    int id = blockIdx.x + gridDim.x * blockIdx.y;
    int xcd = id & 7, k = id >> 3;
    by = k % gridDim.y;
    bx = xcd * (gridDim.x >> 3) + k / gridDim.y;
  }
  const int m0 = bx * 128, n0 = by * 128;
  const int wm = (w >> 1) * 64, wn = (w & 1) * 64;
  const int rowA = tid >> 2, ko = (tid & 3) * 8;

  f32x4 acc[4][4] = {};
  const int sb0 = w * 512, sb1 = 2048 + w * 512;
  const int fA = (wm + (l & 15)) * 32 + (l >> 4) * 8;
  const int fW = (wn + (l & 15)) * 32 + (l >> 4) * 8;

  const unsigned short* gah0 = Ahi + (size_t)(m0 + rowA) * Kd + ko;
  const unsigned short* gah1 = Ahi + (size_t)(m0 + 64 + rowA) * Kd + ko;
  const unsigned short* gwh0 = Whi + (size_t)(n0 + rowA) * Kd + ko;
  const unsigned short* gwh1 = Whi + (size_t)(n0 + 64 + rowA) * Kd + ko;
  const unsigned short* gwl0 = Wlo + (size_t)(n0 + rowA) * Kd + ko;
  const unsigned short* gwl1 = Wlo + (size_t)(n0 + 64 + rowA) * Kd + ko;
  const unsigned short* gal0 = nullptr;
  const unsigned short* gal1 = nullptr;
  if (NPASS == 3) {
    gal0 = Alo + (size_t)(m0 + rowA) * Kd + ko;
    gal1 = Alo + (size_t)(m0 + 64 + rowA) * Kd + ko;
  }

#pragma unroll 1
  for (int kt = 0; kt < Kd; kt += 32) {
    __syncthreads();
    stage16(gah0 + kt, Ahs + sb0);
    stage16(gah1 + kt, Ahs + sb1);
    stage16(gwh0 + kt, Whs + sb0);
    stage16(gwh1 + kt, Whs + sb1);
    stage16(gwl0 + kt, Wls + sb0);
    stage16(gwl1 + kt, Wls + sb1);
    if (NPASS == 3) {
      stage16(gal0 + kt, Als + sb0);
      stage16(gal1 + kt, Als + sb1);
    }
    __syncthreads();
    bf16x8 ah[4], wh[4], wl[4];
#pragma unroll
    for (int i = 0; i < 4; ++i) {
      ah[i] = ldfrag(Ahs + fA + i * 512);
      wh[i] = ldfrag(Whs + fW + i * 512);
      wl[i] = ldfrag(Wls + fW + i * 512);
    }
#pragma unroll
    for (int i = 0; i < 4; ++i)
#pragma unroll
      for (int j = 0; j < 4; ++j)
        acc[i][j] = __builtin_amdgcn_mfma_f32_16x16x32_bf16(ah[i], wh[j], acc[i][j], 0, 0, 0);
#pragma unroll
    for (int i = 0; i < 4; ++i)
#pragma unroll
      for (int j = 0; j < 4; ++j)
        acc[i][j] = __builtin_amdgcn_mfma_f32_16x16x32_bf16(ah[i], wl[j], acc[i][j], 0, 0, 0);
    if (NPASS == 3) {
      bf16x8 al[4];
#pragma unroll
      for (int i = 0; i < 4; ++i) al[i] = ldfrag(Als + fA + i * 512);
#pragma unroll
      for (int i = 0; i < 4; ++i)
#pragma unroll
        for (int j = 0; j < 4; ++j)
          acc[i][j] = __builtin_amdgcn_mfma_f32_16x16x32_bf16(al[i], wh[j], acc[i][j], 0, 0, 0);
    }
  }

  const int cl = l & 15, rg = (l >> 4) * 4;
  float bvv[4];
#pragma unroll
  for (int j = 0; j < 4; ++j) bvv[j] = bias[n0 + wn + j * 16 + cl];
#pragma unroll
  for (int i = 0; i < 4; ++i) {
    const int row = m0 + wm + i * 16 + rg;
#pragma unroll
    for (int r = 0; r < 4; ++r) {
#pragma unroll
      for (int j = 0; j < 4; ++j) {
        float v = acc[i][j][r] + bvv[j];
        if (OUTBF16) {
          ((unsigned short*)Cout)[(size_t)(row + r) * N + n0 + wn + j * 16 + cl] = f2b(v);
        } else {
          ((float*)Cout)[(size_t)(row + r) * N + n0 + wn + j * 16 + cl] = v;
        }
      }
    }
  }
}

// ---------------- Vb [t*8+b][h*128+d] -> VbT [(b*8+h)*128+d][t]
__global__ __launch_bounds__(256) void vtrans_kernel(
    const unsigned short* __restrict__ Vb, unsigned short* __restrict__ VbT)
{
  __shared__ __align__(16) unsigned short T[128 * 132];
  const int tt = blockIdx.x, b = blockIdx.y, h = blockIdx.z;
  const int tid = threadIdx.x;
  {
    int t = tid >> 1, f0 = (tid & 1) * 64;
    const unsigned short* gp = Vb + ((size_t)((tt * 128 + t) * BB + b)) * EE + h * DD + f0;
    unsigned short* lp = T + t * 132 + f0;
#pragma unroll
    for (int k8 = 0; k8 < 8; ++k8) {
      u16x8 v = *(const u16x8*)(gp + k8 * 8);
      u16x4 vl = __builtin_shufflevector(v, v, 0, 1, 2, 3);
      u16x4 vh = __builtin_shufflevector(v, v, 4, 5, 6, 7);
      *(u16x4*)(lp + k8 * 8) = vl;
      *(u16x4*)(lp + k8 * 8 + 4) = vh;
    }
  }
  __syncthreads();
  const size_t obase = ((size_t)(b * HH + h) * DD) * 4096 + tt * 128;
#pragma unroll
  for (int dd = 0; dd < 4; ++dd) {
    int d = (tid >> 3) + dd * 32;
    int t0 = (tid & 7) * 16;
    u16x8 o0, o1;
#pragma unroll
    for (int e = 0; e < 8; ++e) {
      o0[e] = T[(t0 + e) * 132 + d];
      o1[e] = T[(t0 + 8 + e) * 132 + d];
    }
    *(u16x8*)(VbT + obase + (size_t)d * 4096 + t0) = o0;
    *(u16x8*)(VbT + obase + (size_t)d * 4096 + t0 + 8) = o1;
  }
}

// ---------------- den1: Z1[(bh*NC+c)*128 + f] = sum_{j in chunk} phik[j][f]  (fp32)
__global__ __launch_bounds__(256) void den1_kernel(
    const float* __restrict__ Pk, float* __restrict__ Z1)
{
  __shared__ float red[4][130];
  const int c = blockIdx.x, b = blockIdx.y, h = blockIdx.z;
  const int tid = threadIdx.x;
  const int k = tid & 63, part = tid >> 6;
  float ss = 0.f, cs = 0.f;
  const float* pb = Pk + ((size_t)(c * CH) * BB + b) * NPROJ + h * KK + k;
  for (int j = part * 32; j < part * 32 + 32; ++j) {
    float p = pb[(size_t)j * BB * NPROJ];
    float sv, cv; sincosf(p, &sv, &cv);
    ss += sv; cs += cv;
  }
  red[part][k] = ss * 0.125f;
  red[part][k + 65] = cs * 0.125f;
  __syncthreads();
  if (tid < 128) {
    int f = tid;
    int idx = (f < 64) ? f : (f + 1);
    float s = red[0][idx] + red[1][idx] + red[2][idx] + red[3][idx];
    Z1[((size_t)(b * HH + h) * NC + c) * 128 + f] = s;
  }
}

// ---------------- zscan: exclusive prefix of Z1 over chunks, per (bh, f)
__global__ __launch_bounds__(256) void zscan_kernel(float* __restrict__ Z1)
{
  int gid = blockIdx.x * 256 + threadIdx.x;
  if (gid >= 64 * 128) return;
  int bh = gid >> 7, f = gid & 127;
  float* p = Z1 + (size_t)bh * NC * 128 + f;
  float run = 0.f;
#pragma unroll
  for (int cc = 0; cc < NC; ++cc) {
    float t = p[cc * 128];
    p[cc * 128] = run;
    run += t;
  }
}

// ---------------- den2: Den[bh*TT + c*128 + row] = phiq[row] . (Z1_prefix + cumsum_{j<=row} phik[j])
// Byproducts (bit-identical to the old phicast): Phk, Phq bf16 buffers.
__global__ __launch_bounds__(256) void den2_kernel(
    const float* __restrict__ Pq, const float* __restrict__ Pk,
    const float* __restrict__ Z1, float* __restrict__ Den,
    unsigned short* __restrict__ Phq, unsigned short* __restrict__ Phk)
{
  __shared__ float Ks[128][132];
  const int c = blockIdx.x, b = blockIdx.y, h = blockIdx.z;
  const int tid = threadIdx.x;
  const int bh = b * HH + h;
  {  // phase 1: Ks[j][f] = phik[j][f]; also emit Phk bf16
    int j = tid >> 1, k0 = (tid & 1) * 32;
    const float* pp = Pk + ((size_t)(c * CH + j) * BB + b) * NPROJ + h * KK + k0;
    unsigned short* gk = Phk + ((size_t)(c * CH + j) * BB + b) * EE + h * PHI2;
#pragma unroll
    for (int k4 = 0; k4 < 32; k4 += 4) {
      float4 p = *(const float4*)(pp + k4);
      float sv, cv;
      ushort4 so, co;
      sincosf(p.x, &sv, &cv);
      Ks[j][k0 + k4 + 0] = sv * 0.125f; Ks[j][64 + k0 + k4 + 0] = cv * 0.125f;
      so.x = f2b(sv * 0.125f); co.x = f2b(cv * 0.125f);
      sincosf(p.y, &sv, &cv);
      Ks[j][k0 + k4 + 1] = sv * 0.125f; Ks[j][64 + k0 + k4 + 1] = cv * 0.125f;
      so.y = f2b(sv * 0.125f); co.y = f2b(cv * 0.125f);
      sincosf(p.z, &sv, &cv);
      Ks[j][k0 + k4 + 2] = sv * 0.125f; Ks[j][64 + k0 + k4 + 2] = cv * 0.125f;
      so.z = f2b(sv * 0.125f); co.z = f2b(cv * 0.125f);
      sincosf(p.w, &sv, &cv);
      Ks[j][k0 + k4 + 3] = sv * 0.125f; Ks[j][64 + k0 + k4 + 3] = cv * 0.125f;
      so.w = f2b(sv * 0.125f); co.w = f2b(cv * 0.125f);
      *(ushort4*)(gk + k0 + k4) = so;
      *(ushort4*)(gk + 64 + k0 + k4) = co;
    }
  }
  __syncthreads();
  if (tid < 128) {  // phase 2: inclusive cumsum down j, seeded with exclusive chunk prefix
    int f = tid;
    float run = Z1[((size_t)bh * NC + c) * 128 + f];
    for (int j = 0; j < 128; ++j) { run += Ks[j][f]; Ks[j][f] = run; }
  }
  __syncthreads();
  {  // phase 3: den[row] = sum_f phiq[row][f] * Ks[row][f]; also emit Phq bf16
    int row = tid >> 1, half = tid & 1;
    const float* pq = Pq + ((size_t)(c * CH + row) * BB + b) * NPROJ + h * KK;
    unsigned short* gq = Phq + ((size_t)(c * CH + row) * BB + b) * EE + h * PHI2 + half * 64;
    float accd = 0.f;
#pragma unroll
    for (int k8 = 0; k8 < 8; ++k8) {
      u16x8 ov;
#pragma unroll
      for (int e = 0; e < 8; ++e) {
        int k = k8 * 8 + e;
        float sv, cv; sincosf(pq[k], &sv, &cv);
        float phi = (half ? cv : sv) * 0.125f;
        ov[e] = f2b(phi);
        accd = fmaf(phi, Ks[row][half * 64 + k], accd);
      }
      *(u16x8*)(gq + k8 * 8) = ov;
    }
    accd += __shfl_xor(accd, 1);
    if (half == 0) Den[(size_t)bh * TT + c * CH + row] = accd;
  }
}

// ---------------- pass1 (MFMA): St_c[d][f] = sum_j VbT[d][j]*phik[j][f]
__global__ __launch_bounds__(256) void pass1_mfma(
    const unsigned short* __restrict__ Phk, const unsigned short* __restrict__ VbT,
    unsigned short* __restrict__ St)
{
  __shared__ __align__(16) unsigned short KT[128 * 132];  // [f][j]
  __shared__ __align__(16) unsigned short Am[128 * 40];   // [d][32 j] stream
  const int c = blockIdx.x, b = blockIdx.y, h = blockIdx.z;
  const int tid = threadIdx.x;
  const int w = tid >> 6, l = tid & 63;
  const int wm = (w >> 1) * 64, wn = (w & 1) * 64;
  const int cl = l & 15, ks = l >> 4;
  const int bh = b * HH + h;

  {  // transpose-stage phi_k tile into KT[f][j]
    int j = tid >> 1, f0 = (tid & 1) * 64;
    const unsigned short* gp = Phk + ((size_t)(c * CH + j) * BB + b) * EE + h * PHI2 + f0;
#pragma unroll
    for (int k8 = 0; k8 < 8; ++k8) {
      u16x8 v = *(const u16x8*)(gp + k8 * 8);
#pragma unroll
      for (int e = 0; e < 8; ++e) KT[(f0 + k8 * 8 + e) * 132 + j] = v[e];
    }
  }

  f32x4 acc[4][4] = {};
  const unsigned short* vbase = VbT + (size_t)bh * DD * 4096 + c * CH;
#pragma unroll 1
  for (int j0 = 0; j0 < 128; j0 += 32) {
    __syncthreads();
    stage_rs(vbase + j0, 4096, Am, tid);
    __syncthreads();
    bf16x8 af[4], wf[4];
#pragma unroll
    for (int i = 0; i < 4; ++i) {
      af[i] = ldfrag(Am + (wm + cl + i * 16) * 40 + ks * 8);
      wf[i] = ldfrag64(KT + (wn + cl + i * 16) * 132 + j0 + ks * 8);
    }
#pragma unroll
    for (int i = 0; i < 4; ++i)
#pragma unroll
      for (int j = 0; j < 4; ++j)
        acc[i][j] = __builtin_amdgcn_mfma_f32_16x16x32_bf16(af[i], wf[j], acc[i][j], 0, 0, 0);
  }
  unsigned short* sp = St + (size_t)(bh * NC + c) * (DD * PHI2);
#pragma unroll
  for (int i = 0; i < 4; ++i) {
    int d = wm + i * 16 + ks * 4;
#pragma unroll
    for (int r = 0; r < 4; ++r) {
#pragma unroll
      for (int j = 0; j < 4; ++j)
        sp[(size_t)(d + r) * PHI2 + wn + j * 16 + cl] = f2b(acc[i][j][r]);
    }
  }
}

// ---------------- sscan: exclusive prefix over chunks of St (bf16, fp32 carry)
__global__ __launch_bounds__(256) void sscan_kernel(unsigned short* __restrict__ Sb)
{
  int gid = blockIdx.x * 256 + threadIdx.x;
  if (gid >= 64 * CH * DD) return;
  int bh = gid >> 14, fd = gid & 16383;
  unsigned short* p = Sb + (size_t)bh * NC * 16384 + fd;
  float run = 0.f;
#pragma unroll
  for (int cc = 0; cc < NC; ++cc) {
    float t = b2f(p[(size_t)cc * 16384]);
    p[(size_t)cc * 16384] = f2b(run);
    run += t;
  }
}

// ---------------- attn (MFMA): per (c,b,h)
// sc = phiq @ phik^T (causal); num = sc @ VbT^T + phiq @ St^T; Ob = num / max(Den, eps)
__global__ __launch_bounds__(256) void attn_mfma(
    const unsigned short* __restrict__ Phq, const unsigned short* __restrict__ Phk,
    const unsigned short* __restrict__ VbT, const unsigned short* __restrict__ St,
    const float* __restrict__ Den, unsigned short* __restrict__ Ob)
{
  __shared__ __align__(16) unsigned short Qs[128 * 132];
  __shared__ __align__(16) unsigned short sc[128 * 132];
  __shared__ __align__(16) unsigned short Sm[128 * 40];
  __shared__ float den_s[128];
  const int c = blockIdx.x, b = blockIdx.y, h = blockIdx.z;
  const int tid = threadIdx.x;
  const int w = tid >> 6, l = tid & 63;
  const int wm = (w >> 1) * 64, wn = (w & 1) * 64;
  const int cl = l & 15, ks = l >> 4;
  const int bh = b * HH + h;

  {  // stage phi_q tile
    int r = tid >> 1, f0 = (tid & 1) * 64;
    const unsigned short* gp = Phq + ((size_t)(c * CH + r) * BB + b) * EE + h * PHI2 + f0;
    unsigned short* lp = Qs + r * 132 + f0;
#pragma unroll
    for (int k8 = 0; k8 < 8; ++k8) {
      u16x8 v = *(const u16x8*)(gp + k8 * 8);
      u16x4 vl = __builtin_shufflevector(v, v, 0, 1, 2, 3);
      u16x4 vh = __builtin_shufflevector(v, v, 4, 5, 6, 7);
      *(u16x4*)(lp + k8 * 8) = vl;
      *(u16x4*)(lp + k8 * 8 + 4) = vh;
    }
  }
  if (tid < 128) den_s[tid] = Den[(size_t)bh * TT + c * CH + tid];

  f32x4 acc[4][4] = {};
  // ---- phase A: scores
  const unsigned short* kbase = Phk + ((size_t)(c * CH) * BB + b) * EE + h * PHI2;
#pragma unroll 1
  for (int ft = 0; ft < PHI2; ft += 32) {
    __syncthreads();
    stage_rs(kbase + ft, (size_t)BB * EE, Sm, tid);
    __syncthreads();
    if (w != 1) {  // wave (rows 0-63, cols 64-127) fully masked -> skip
      bf16x8 af[4], wf[4];
#pragma unroll
      for (int i = 0; i < 4; ++i) {
        af[i] = ldfrag64(Qs + (wm + cl + i * 16) * 132 + ft + ks * 8);
        wf[i] = ldfrag(Sm + (wn + cl + i * 16) * 40 + ks * 8);
      }
#pragma unroll
      for (int i = 0; i < 4; ++i)
#pragma unroll
        for (int j = 0; j < 4; ++j)
          acc[i][j] = __builtin_amdgcn_mfma_f32_16x16x32_bf16(af[i], wf[j], acc[i][j], 0, 0, 0);
    }
  }
  __syncthreads();
#pragma unroll
  for (int i = 0; i < 4; ++i) {
    int row0 = wm + i * 16 + ks * 4;
#pragma unroll
    for (int r = 0; r < 4; ++r) {
      int row = row0 + r;
#pragma unroll
      for (int j = 0; j < 4; ++j) {
        int col = wn + j * 16 + cl;
        sc[row * 132 + col] = f2b((col <= row) ? acc[i][j][r] : 0.f);
      }
    }
  }
  __syncthreads();

  // ---- phase B
#pragma unroll
  for (int i = 0; i < 4; ++i)
#pragma unroll
    for (int j = 0; j < 4; ++j) acc[i][j] = (f32x4){0.f, 0.f, 0.f, 0.f};

  const unsigned short* vbase = VbT + (size_t)bh * DD * 4096 + c * CH;
#pragma unroll 1
  for (int j0 = 0; j0 < 128; j0 += 32) {
    __syncthreads();
    stage_rs(vbase + j0, 4096, Sm, tid);
    __syncthreads();
    if (!(wm == 0 && j0 >= 64)) {
      bf16x8 af[4], wf[4];
#pragma unroll
      for (int i = 0; i < 4; ++i) {
        af[i] = ldfrag64(sc + (wm + cl + i * 16) * 132 + j0 + ks * 8);
        wf[i] = ldfrag(Sm + (wn + cl + i * 16) * 40 + ks * 8);
      }
#pragma unroll
      for (int i = 0; i < 4; ++i)
#pragma unroll
        for (int j = 0; j < 4; ++j)
          acc[i][j] = __builtin_amdgcn_mfma_f32_16x16x32_bf16(af[i], wf[j], acc[i][j], 0, 0, 0);
    }
  }
  const unsigned short* sbase = St + (size_t)(bh * NC + c) * (DD * PHI2);
#pragma unroll 1
  for (int f0 = 0; f0 < PHI2; f0 += 32) {
    __syncthreads();
    stage_rs(sbase + f0, PHI2, Sm, tid);
    __syncthreads();
    bf16x8 af[4], wf[4];
#pragma unroll
    for (int i = 0; i < 4; ++i) {
      af[i] = ldfrag64(Qs + (wm + cl + i * 16) * 132 + f0 + ks * 8);
      wf[i] = ldfrag(Sm + (wn + cl + i * 16) * 40 + ks * 8);
    }
#pragma unroll
    for (int i = 0; i < 4; ++i)
#pragma unroll
      for (int j = 0; j < 4; ++j)
        acc[i][j] = __builtin_amdgcn_mfma_f32_16x16x32_bf16(af[i], wf[j], acc[i][j], 0, 0, 0);
  }
#pragma unroll
  for (int i = 0; i < 4; ++i) {
    int row0 = wm + i * 16 + ks * 4;
#pragma unroll
    for (int r = 0; r < 4; ++r) {
      int row = row0 + r;
      float inv = 1.0f / fmaxf(den_s[row], EPSV);
      unsigned short* op = Ob + ((size_t)(c * CH + row) * BB + b) * EE + h * DD;
#pragma unroll
      for (int j = 0; j < 4; ++j)
        op[wn + j * 16 + cl] = f2b(acc[i][j][r] * inv);
    }
  }
}

extern "C" void kernel_launch(void* const* d_in, const int* in_sizes, int n_in,
                              void* d_out, int out_size, void* d_ws, size_t ws_size,
                              hipStream_t stream)
{
  const float* x     = (const float*)d_in[0];
  const float* rmat  = (const float*)d_in[1];
  const float* Wq    = (const float*)d_in[2];
  const float* bq    = (const float*)d_in[3];
  const float* Wk    = (const float*)d_in[4];
  const float* bk    = (const float*)d_in[5];
  const float* Wv    = (const float*)d_in[6];
  const float* bv    = (const float*)d_in[7];
  const float* Wo    = (const float*)d_in[8];
  const float* bo    = (const float*)d_in[9];
  const float* sigma = (const float*)d_in[10];

  // ---- workspace (256 MiB), lifetimes stream-ordered:
  //   [0,  64Mi): pq_p fp32 (steps 4-10)  -> St bf16 (pass1 out, steps 11-13)
  //   [64,128Mi): pk_p fp32 (steps 5-10)  -> Ob bf16 (attn out, steps 13-15)
  //   [128,192Mi): Vb bf16 (steps 6-7)    -> Z1 @128Mi, Den @129Mi, Woh @130Mi, Wol @132Mi
  //   [240,256Mi): Weff fp32 + biases + weight splits (steps 2-6)
  //   [192,256Mi): VbT bf16 (vtrans out, steps 7-13; overwrites weights after step 6)
  // ---- d_out (128 MiB):
  //   xhi [0,64Mi), xlo [64,128Mi) (steps 1-6) -> Phq [0,64Mi), Phk [64,128Mi)
  //   (den2 out, steps 10-13) -> final fp32 output (step 15)
  char* wsb = (char*)d_ws;
  float* pq_p = (float*)wsb;
  float* pk_p = (float*)(wsb + (64LL << 20));
  unsigned short* Stb = (unsigned short*)wsb;
  unsigned short* Ob  = (unsigned short*)(wsb + (64LL << 20));
  unsigned short* Vb  = (unsigned short*)(wsb + (128LL << 20));
  float* Z1  = (float*)(wsb + (128LL << 20));
  float* Den = (float*)(wsb + (129LL << 20));
  unsigned short* Woh = (unsigned short*)(wsb + (130LL << 20));
  unsigned short* Wol = (unsigned short*)(wsb + (132LL << 20));
  unsigned short* VbT = (unsigned short*)(wsb + (192LL << 20));
  float* Weq = (float*)(wsb + (240LL << 20));
  float* Wek = (float*)(wsb + (242LL << 20));
  float* beq = (float*)(wsb + (244LL << 20));
  float* bek = (float*)(wsb + (244LL << 20) + 65536);
  unsigned short* Weqh = (unsigned short*)(wsb + (245LL << 20));
  unsigned short* Weql = (unsigned short*)(wsb + (246LL << 20));
  unsigned short* Wekh = (unsigned short*)(wsb + (247LL << 20));
  unsigned short* Wekl = (unsigned short*)(wsb + (248LL << 20));
  unsigned short* Wvh  = (unsigned short*)(wsb + (249LL << 20));
  unsigned short* Wvl  = (unsigned short*)(wsb + (251LL << 20));

  char* ob = (char*)d_out;
  unsigned short* xhi = (unsigned short*)ob;
  unsigned short* xlo = (unsigned short*)(ob + (64LL << 20));
  unsigned short* Phq = (unsigned short*)ob;
  unsigned short* Phk = (unsigned short*)(ob + (64LL << 20));

  dim3 bt(256);
  // 1-3: casts + effective projection weights + splits
  hipLaunchKernelGGL(split_kernel, dim3(2048), bt, 0, stream, x, xhi, xlo, NROWS * EE / 4);
  hipLaunchKernelGGL(weff_kernel, dim3(8, 8), bt, 0, stream, rmat, sigma, Wq, bq, Weq, beq);
  hipLaunchKernelGGL(weff_kernel, dim3(8, 8), bt, 0, stream, rmat, sigma, Wk, bk, Wek, bek);
  hipLaunchKernelGGL(split_kernel, dim3(512), bt, 0, stream, Weq, Weqh, Weql, NPROJ * EE / 4);
  hipLaunchKernelGGL(split_kernel, dim3(512), bt, 0, stream, Wek, Wekh, Wekl, NPROJ * EE / 4);
  hipLaunchKernelGGL(split_kernel, dim3(1024), bt, 0, stream, Wv, Wvh, Wvl, EE * EE / 4);
  // 4-6: projections (fp32 p for q/k 3-pass; bf16 V 2-pass — error ~0.1% rms < bf16 out rounding)
  hipLaunchKernelGGL((gemm_mfma<0, 3>), dim3(NROWS / 128, NPROJ / 128), bt, 0, stream,
                     xhi, xlo, Weqh, Weql, beq, (void*)pq_p, NROWS, NPROJ, EE);
  hipLaunchKernelGGL((gemm_mfma<0, 3>), dim3(NROWS / 128, NPROJ / 128), bt, 0, stream,
                     xhi, xlo, Wekh, Wekl, bek, (void*)pk_p, NROWS, NPROJ, EE);
  hipLaunchKernelGGL((gemm_mfma<1, 2>), dim3(NROWS / 128, EE / 128), bt, 0, stream,
                     xhi, (const unsigned short*)0, Wvh, Wvl, bv, (void*)Vb, NROWS, EE, EE);
  // 7: V transpose (Vb dead after; VbT overwrites weight region — weights dead)
  hipLaunchKernelGGL(vtrans_kernel, dim3(NC, BB, HH), bt, 0, stream, Vb, VbT);
  // 8-10: fp32 denominator path; den2 also emits Phq/Phk bf16 (xhi/xlo dead)
  hipLaunchKernelGGL(den1_kernel, dim3(NC, BB, HH), bt, 0, stream, pk_p, Z1);
  hipLaunchKernelGGL(zscan_kernel, dim3(32), bt, 0, stream, Z1);
  hipLaunchKernelGGL(den2_kernel, dim3(NC, BB, HH), bt, 0, stream, pq_p, pk_p, Z1, Den, Phq, Phk);
  // 11-12: chunk states + exclusive scan (pq_p dead -> St)
  hipLaunchKernelGGL(pass1_mfma, dim3(NC, BB, HH), bt, 0, stream, Phk, VbT, Stb);
  hipLaunchKernelGGL(sscan_kernel, dim3(4096), bt, 0, stream, Stb);
  // 13: attention (pk_p dead -> Ob)
  hipLaunchKernelGGL(attn_mfma, dim3(NC, BB, HH), bt, 0, stream, Phq, Phk, VbT, Stb, Den, Ob);
  // 14-15: output projection
  hipLaunchKernelGGL(split_kernel, dim3(1024), bt, 0, stream, Wo, Woh, Wol, EE * EE / 4);
  hipLaunchKernelGGL((gemm_mfma<0, 2>), dim3(NROWS / 128, EE / 128), bt, 0, stream,
                     Ob, (const unsigned short*)0, Woh, Wol, bo, (void*)d_out, NROWS, EE, EE);
}

// Round 6
// 1182.785 us; speedup vs baseline: 3.0708x; 1.1279x over previous
//
#include <hip/hip_runtime.h>
#include <math.h>

#define TT 4096
#define BB 8
#define EE 1024
#define HH 8
#define DD 128
#define KK 64        // proj dim per head
#define PHI2 128     // 2K features per head
#define NPROJ 512    // H*K total pre-sincos width
#define CH 128
#define NC 32
#define NROWS 32768
#define EPSV 1e-6f

typedef float f32x4 __attribute__((ext_vector_type(4)));
typedef __bf16 bf16x8 __attribute__((ext_vector_type(8)));
typedef unsigned short u16x8 __attribute__((ext_vector_type(8)));
typedef unsigned short u16x4 __attribute__((ext_vector_type(4)));

__device__ __forceinline__ unsigned short f2b(float f) {
  union { float f; unsigned int u; } v; v.f = f;
  unsigned int u = v.u;
  u += 0x7fffu + ((u >> 16) & 1u);
  return (unsigned short)(u >> 16);
}
__device__ __forceinline__ float b2f(unsigned short h) {
  union { float f; unsigned int u; } v; v.u = ((unsigned int)h) << 16;
  return v.f;
}
// native sin/cos: |err| ~1e-6 for |x|<~16 — below bf16 quantum, negligible in fp32 den.
__device__ __forceinline__ void fast_sc(float x, float& s, float& c) {
  s = __sinf(x); c = __cosf(x);
}

// async global->LDS, 16B per lane; lds ptr must be wave-uniform (HW writes base+lane*16).
__device__ __forceinline__ void stage16(const void* g, void* l) {
  __builtin_amdgcn_global_load_lds(
      (const __attribute__((address_space(1))) void*)g,
      (__attribute__((address_space(3))) void*)l, 16, 0, 0);
}

__device__ __forceinline__ bf16x8 ldfrag(const unsigned short* p) {  // 16B-aligned
  u16x8 s = *(const u16x8*)p;
  return __builtin_bit_cast(bf16x8, s);
}
__device__ __forceinline__ bf16x8 ldfrag64(const unsigned short* p) {  // 8B-aligned (pitch-132 LDS)
  u16x4 a = *(const u16x4*)p;
  u16x4 b = *(const u16x4*)(p + 4);
  u16x8 v = {a[0], a[1], a[2], a[3], b[0], b[1], b[2], b[3]};
  return __builtin_bit_cast(bf16x8, v);
}

// stream-stage [128 rows][32 cols] bf16 from global (row stride rstride shorts)
// into LDS pitch 40 (80B rows, 16B-aligned). all 256 threads.
__device__ __forceinline__ void stage_rs(const unsigned short* gbase, size_t rstride,
                                         unsigned short* lds, int tid)
{
  int r = tid >> 1, c0 = (tid & 1) * 16;
  const unsigned short* gp = gbase + (size_t)r * rstride + c0;
  u16x8 v0 = *(const u16x8*)gp;
  u16x8 v1 = *(const u16x8*)(gp + 8);
  *(u16x8*)(lds + r * 40 + c0) = v0;
  *(u16x8*)(lds + r * 40 + c0 + 8) = v1;
}

// ---- split fp32 -> bf16 hi + bf16 lo (residual), vectorized x4
__global__ __launch_bounds__(256) void split_kernel(
    const float* __restrict__ in, unsigned short* __restrict__ hi,
    unsigned short* __restrict__ lo, int n4)
{
  int stride = gridDim.x * 256;
  for (int i = blockIdx.x * 256 + threadIdx.x; i < n4; i += stride) {
    float4 v = ((const float4*)in)[i];
    ushort4 h, l;
    h.x = f2b(v.x); l.x = f2b(v.x - b2f(h.x));
    h.y = f2b(v.y); l.y = f2b(v.y - b2f(h.y));
    h.z = f2b(v.z); l.z = f2b(v.z - b2f(h.z));
    h.w = f2b(v.w); l.w = f2b(v.w - b2f(h.w));
    ((ushort4*)hi)[i] = h;
    ((ushort4*)lo)[i] = l;
  }
}

// ---- Weff[h*64+k][e] = sum_d s4*sigma[h,d]*rm[h,k,d]*W[h*128+d][e]; beff likewise from b.
__global__ __launch_bounds__(256) void weff_kernel(
    const float* __restrict__ rmat, const float* __restrict__ sigma,
    const float* __restrict__ W, const float* __restrict__ bvec,
    float* __restrict__ Weff, float* __restrict__ beff)
{
  __shared__ float rme[64][130];
  __shared__ float Wt[128][130];
  const int et = blockIdx.x;
  const int h  = blockIdx.y;
  const int tid = threadIdx.x;
  const int e0 = et * 128;
  const float s4 = 0.29730177875068026f;  // 128^-0.25

  for (int f = tid; f < 64 * 32; f += 256) {
    int kk = f >> 5, d = (f & 31) * 4;
    float4 rv = *(const float4*)(rmat + ((size_t)(h * 64 + kk)) * 128 + d);
    const float* sg = sigma + h * 128 + d;
    rme[kk][d + 0] = rv.x * sg[0] * s4;
    rme[kk][d + 1] = rv.y * sg[1] * s4;
    rme[kk][d + 2] = rv.z * sg[2] * s4;
    rme[kk][d + 3] = rv.w * sg[3] * s4;
  }
  for (int f = tid; f < 128 * 32; f += 256) {
    int dd = f >> 5, e = (f & 31) * 4;
    *(float4*)&Wt[dd][e] = *(const float4*)(W + ((size_t)(h * 128 + dd)) * EE + e0 + e);
  }
  __syncthreads();
  const int nl = tid >> 2;
  const int el0 = (tid & 3) * 32;
  for (int e = 0; e < 32; ++e) {
    float acc = 0.f;
#pragma unroll
    for (int d = 0; d < 128; ++d)
      acc = fmaf(rme[nl][d], Wt[d][el0 + e], acc);
    Weff[(size_t)(h * 64 + nl) * EE + e0 + el0 + e] = acc;
  }
  if (et == 0 && tid < 64) {
    float acc = 0.f;
    for (int d = 0; d < 128; ++d)
      acc = fmaf(rme[tid][d], bvec[h * 128 + d], acc);
    beff[h * 64 + tid] = acc;
  }
}

// ---------------- MFMA GEMM: C[M,N] = A[M,K] @ W[N,K]^T + bias[N]
// fp32 split compensation fused in one K-loop:
//   NPASS=3: acc += Ahi*Whi + Ahi*Wlo + Alo*Whi ; NPASS=2: acc += Ahi*(Whi + Wlo)
// m97 structure: 128x128 tile, BK=32, 4 waves (2x2), 4x4 16x16x32 frags/wave.
// Grid is XCD-swizzled (bijective; requires gridDim.x % 8 == 0).
template<int OUTBF16, int NPASS>
__global__ __launch_bounds__(256) void gemm_mfma(
    const unsigned short* __restrict__ Ahi, const unsigned short* __restrict__ Alo,
    const unsigned short* __restrict__ Whi, const unsigned short* __restrict__ Wlo,
    const float* __restrict__ bias, void* __restrict__ Cout, int M, int N, int Kd)
{
  __shared__ __align__(16) unsigned short Ahs[128 * 32];
  __shared__ __align__(16) unsigned short Whs[128 * 32];
  __shared__ __align__(16) unsigned short Wls[128 * 32];
  __shared__ __align__(16) unsigned short Als[NPASS == 3 ? 128 * 32 : 8];
  const int tid = threadIdx.x;
  const int w = tid >> 6, l = tid & 63;
  // XCD-aware bijective swizzle: same-M-tile blocks adjacent on one XCD.
  int bx, by;
  {
    int id = blockIdx.x + gridDim.x * blockIdx.y;
    int xcd = id & 7, k = id >> 3;
    by = k % gridDim.y;
    bx = xcd * (gridDim.x >> 3) + k / gridDim.y;
  }
  const int m0 = bx * 128, n0 = by * 128;
  const int wm = (w >> 1) * 64, wn = (w & 1) * 64;
  const int rowA = tid >> 2, ko = (tid & 3) * 8;

  f32x4 acc[4][4] = {};
  const int sb0 = w * 512, sb1 = 2048 + w * 512;
  const int fA = (wm + (l & 15)) * 32 + (l >> 4) * 8;
  const int fW = (wn + (l & 15)) * 32 + (l >> 4) * 8;

  const unsigned short* gah0 = Ahi + (size_t)(m0 + rowA) * Kd + ko;
  const unsigned short* gah1 = Ahi + (size_t)(m0 + 64 + rowA) * Kd + ko;
  const unsigned short* gwh0 = Whi + (size_t)(n0 + rowA) * Kd + ko;
  const unsigned short* gwh1 = Whi + (size_t)(n0 + 64 + rowA) * Kd + ko;
  const unsigned short* gwl0 = Wlo + (size_t)(n0 + rowA) * Kd + ko;
  const unsigned short* gwl1 = Wlo + (size_t)(n0 + 64 + rowA) * Kd + ko;
  const unsigned short* gal0 = nullptr;
  const unsigned short* gal1 = nullptr;
  if (NPASS == 3) {
    gal0 = Alo + (size_t)(m0 + rowA) * Kd + ko;
    gal1 = Alo + (size_t)(m0 + 64 + rowA) * Kd + ko;
  }

#pragma unroll 1
  for (int kt = 0; kt < Kd; kt += 32) {
    __syncthreads();
    stage16(gah0 + kt, Ahs + sb0);
    stage16(gah1 + kt, Ahs + sb1);
    stage16(gwh0 + kt, Whs + sb0);
    stage16(gwh1 + kt, Whs + sb1);
    stage16(gwl0 + kt, Wls + sb0);
    stage16(gwl1 + kt, Wls + sb1);
    if (NPASS == 3) {
      stage16(gal0 + kt, Als + sb0);
      stage16(gal1 + kt, Als + sb1);
    }
    __syncthreads();
    bf16x8 ah[4], wh[4], wl[4];
#pragma unroll
    for (int i = 0; i < 4; ++i) {
      ah[i] = ldfrag(Ahs + fA + i * 512);
      wh[i] = ldfrag(Whs + fW + i * 512);
      wl[i] = ldfrag(Wls + fW + i * 512);
    }
#pragma unroll
    for (int i = 0; i < 4; ++i)
#pragma unroll
      for (int j = 0; j < 4; ++j)
        acc[i][j] = __builtin_amdgcn_mfma_f32_16x16x32_bf16(ah[i], wh[j], acc[i][j], 0, 0, 0);
#pragma unroll
    for (int i = 0; i < 4; ++i)
#pragma unroll
      for (int j = 0; j < 4; ++j)
        acc[i][j] = __builtin_amdgcn_mfma_f32_16x16x32_bf16(ah[i], wl[j], acc[i][j], 0, 0, 0);
    if (NPASS == 3) {
      bf16x8 al[4];
#pragma unroll
      for (int i = 0; i < 4; ++i) al[i] = ldfrag(Als + fA + i * 512);
#pragma unroll
      for (int i = 0; i < 4; ++i)
#pragma unroll
        for (int j = 0; j < 4; ++j)
          acc[i][j] = __builtin_amdgcn_mfma_f32_16x16x32_bf16(al[i], wh[j], acc[i][j], 0, 0, 0);
    }
  }

  const int cl = l & 15, rg = (l >> 4) * 4;
  float bvv[4];
#pragma unroll
  for (int j = 0; j < 4; ++j) bvv[j] = bias[n0 + wn + j * 16 + cl];
#pragma unroll
  for (int i = 0; i < 4; ++i) {
    const int row = m0 + wm + i * 16 + rg;
#pragma unroll
    for (int r = 0; r < 4; ++r) {
#pragma unroll
      for (int j = 0; j < 4; ++j) {
        float v = acc[i][j][r] + bvv[j];
        if (OUTBF16) {
          ((unsigned short*)Cout)[(size_t)(row + r) * N + n0 + wn + j * 16 + cl] = f2b(v);
        } else {
          ((float*)Cout)[(size_t)(row + r) * N + n0 + wn + j * 16 + cl] = v;
        }
      }
    }
  }
}

// ---------------- Vb [t*8+b][h*128+d] -> VbT [(b*8+h)*128+d][t]
__global__ __launch_bounds__(256) void vtrans_kernel(
    const unsigned short* __restrict__ Vb, unsigned short* __restrict__ VbT)
{
  __shared__ __align__(16) unsigned short T[128 * 132];
  const int tt = blockIdx.x, b = blockIdx.y, h = blockIdx.z;
  const int tid = threadIdx.x;
  {
    int t = tid >> 1, f0 = (tid & 1) * 64;
    const unsigned short* gp = Vb + ((size_t)((tt * 128 + t) * BB + b)) * EE + h * DD + f0;
    unsigned short* lp = T + t * 132 + f0;
#pragma unroll
    for (int k8 = 0; k8 < 8; ++k8) {
      u16x8 v = *(const u16x8*)(gp + k8 * 8);
      u16x4 vl = __builtin_shufflevector(v, v, 0, 1, 2, 3);
      u16x4 vh = __builtin_shufflevector(v, v, 4, 5, 6, 7);
      *(u16x4*)(lp + k8 * 8) = vl;
      *(u16x4*)(lp + k8 * 8 + 4) = vh;
    }
  }
  __syncthreads();
  const size_t obase = ((size_t)(b * HH + h) * DD) * 4096 + tt * 128;
#pragma unroll
  for (int dd = 0; dd < 4; ++dd) {
    int d = (tid >> 3) + dd * 32;
    int t0 = (tid & 7) * 16;
    u16x8 o0, o1;
#pragma unroll
    for (int e = 0; e < 8; ++e) {
      o0[e] = T[(t0 + e) * 132 + d];
      o1[e] = T[(t0 + 8 + e) * 132 + d];
    }
    *(u16x8*)(VbT + obase + (size_t)d * 4096 + t0) = o0;
    *(u16x8*)(VbT + obase + (size_t)d * 4096 + t0 + 8) = o1;
  }
}

// ---------------- den1: Z1[(bh*NC+c)*128 + f] = sum_{j in chunk} phik[j][f]  (fp32)
__global__ __launch_bounds__(256) void den1_kernel(
    const float* __restrict__ Pk, float* __restrict__ Z1)
{
  __shared__ float red[4][130];
  const int c = blockIdx.x, b = blockIdx.y, h = blockIdx.z;
  const int tid = threadIdx.x;
  const int k = tid & 63, part = tid >> 6;
  float ss = 0.f, cs = 0.f;
  const float* pb = Pk + ((size_t)(c * CH) * BB + b) * NPROJ + h * KK + k;
  for (int j = part * 32; j < part * 32 + 32; ++j) {
    float p = pb[(size_t)j * BB * NPROJ];
    float sv, cv; fast_sc(p, sv, cv);
    ss += sv; cs += cv;
  }
  red[part][k] = ss * 0.125f;
  red[part][k + 65] = cs * 0.125f;
  __syncthreads();
  if (tid < 128) {
    int f = tid;
    int idx = (f < 64) ? f : (f + 1);
    float s = red[0][idx] + red[1][idx] + red[2][idx] + red[3][idx];
    Z1[((size_t)(b * HH + h) * NC + c) * 128 + f] = s;
  }
}

// ---------------- zscan: exclusive prefix of Z1 over chunks, per (bh, f)
__global__ __launch_bounds__(256) void zscan_kernel(float* __restrict__ Z1)
{
  int gid = blockIdx.x * 256 + threadIdx.x;
  if (gid >= 64 * 128) return;
  int bh = gid >> 7, f = gid & 127;
  float* p = Z1 + (size_t)bh * NC * 128 + f;
  float run = 0.f;
#pragma unroll
  for (int cc = 0; cc < NC; ++cc) {
    float t = p[cc * 128];
    p[cc * 128] = run;
    run += t;
  }
}

// ---------------- den2: Den[bh*TT + c*128 + row] = phiq[row] . (Z1_prefix + cumsum_{j<=row} phik[j])
// Byproducts: Phk, Phq bf16 buffers, written lane-contiguous (full-sector stores).
__global__ __launch_bounds__(256) void den2_kernel(
    const float* __restrict__ Pq, const float* __restrict__ Pk,
    const float* __restrict__ Z1, float* __restrict__ Den,
    unsigned short* __restrict__ Phq, unsigned short* __restrict__ Phk)
{
  __shared__ float Ks[128][132];
  const int c = blockIdx.x, b = blockIdx.y, h = blockIdx.z;
  const int tid = threadIdx.x;
  const int bh = b * HH + h;
  {  // phase 1: Ks[j][f] = phik[j][f] (LDS only)
    int j = tid >> 1, k0 = (tid & 1) * 32;
    const float* pp = Pk + ((size_t)(c * CH + j) * BB + b) * NPROJ + h * KK + k0;
#pragma unroll
    for (int k4 = 0; k4 < 32; k4 += 4) {
      float4 p = *(const float4*)(pp + k4);
      float sv, cv;
      fast_sc(p.x, sv, cv); Ks[j][k0 + k4 + 0] = sv * 0.125f; Ks[j][64 + k0 + k4 + 0] = cv * 0.125f;
      fast_sc(p.y, sv, cv); Ks[j][k0 + k4 + 1] = sv * 0.125f; Ks[j][64 + k0 + k4 + 1] = cv * 0.125f;
      fast_sc(p.z, sv, cv); Ks[j][k0 + k4 + 2] = sv * 0.125f; Ks[j][64 + k0 + k4 + 2] = cv * 0.125f;
      fast_sc(p.w, sv, cv); Ks[j][k0 + k4 + 3] = sv * 0.125f; Ks[j][64 + k0 + k4 + 3] = cv * 0.125f;
    }
  }
  __syncthreads();
  {  // Phk write-out: 16 lanes cover one row's 16x16B chunks -> 256B contiguous per row
#pragma unroll
    for (int it = 0; it < 8; ++it) {
      int row = (tid >> 4) + it * 16;
      int ch8 = tid & 15;
      f32x4 a = *(const f32x4*)&Ks[row][ch8 * 8];
      f32x4 bb = *(const f32x4*)&Ks[row][ch8 * 8 + 4];
      u16x8 o;
      o[0] = f2b(a[0]); o[1] = f2b(a[1]); o[2] = f2b(a[2]); o[3] = f2b(a[3]);
      o[4] = f2b(bb[0]); o[5] = f2b(bb[1]); o[6] = f2b(bb[2]); o[7] = f2b(bb[3]);
      *(u16x8*)(Phk + ((size_t)(c * CH + row) * BB + b) * EE + h * PHI2 + ch8 * 8) = o;
    }
  }
  __syncthreads();
  if (tid < 128) {  // phase 2: inclusive cumsum down j, seeded with exclusive chunk prefix
    int f = tid;
    float run = Z1[((size_t)bh * NC + c) * 128 + f];
    for (int j = 0; j < 128; ++j) { run += Ks[j][f]; Ks[j][f] = run; }
  }
  __syncthreads();
  {  // phase 3: den[row] = sum_f phiq[row][f] * Ks[row][f];
     // pack phiq bf16 pairs in place into the consumed prefix of Ks[row] (forward pack).
    int row = tid >> 1, half = tid & 1;
    const float* pq = Pq + ((size_t)(c * CH + row) * BB + b) * NPROJ + h * KK;
    float accd = 0.f;
#pragma unroll
    for (int k8 = 0; k8 < 8; ++k8) {
      float4 p0 = *(const float4*)(pq + k8 * 8);
      float4 p1 = *(const float4*)(pq + k8 * 8 + 4);
      float ph[8];
      float sv, cv;
      fast_sc(p0.x, sv, cv); ph[0] = (half ? cv : sv) * 0.125f;
      fast_sc(p0.y, sv, cv); ph[1] = (half ? cv : sv) * 0.125f;
      fast_sc(p0.z, sv, cv); ph[2] = (half ? cv : sv) * 0.125f;
      fast_sc(p0.w, sv, cv); ph[3] = (half ? cv : sv) * 0.125f;
      fast_sc(p1.x, sv, cv); ph[4] = (half ? cv : sv) * 0.125f;
      fast_sc(p1.y, sv, cv); ph[5] = (half ? cv : sv) * 0.125f;
      fast_sc(p1.z, sv, cv); ph[6] = (half ? cv : sv) * 0.125f;
      fast_sc(p1.w, sv, cv); ph[7] = (half ? cv : sv) * 0.125f;
#pragma unroll
      for (int e = 0; e < 8; ++e)
        accd = fmaf(ph[e], Ks[row][half * 64 + k8 * 8 + e], accd);
      // pack 8 phi -> 4 uints at slots [half*64 + k8*4, +4): below all future reads
      float* dst = &Ks[row][half * 64 + k8 * 4];
#pragma unroll
      for (int e2 = 0; e2 < 4; ++e2) {
        unsigned int pk = (unsigned int)f2b(ph[2 * e2]) |
                          ((unsigned int)f2b(ph[2 * e2 + 1]) << 16);
        dst[e2] = __builtin_bit_cast(float, pk);
      }
    }
    accd += __shfl_xor(accd, 1);
    if (half == 0) Den[(size_t)bh * TT + c * CH + row] = accd;
  }
  __syncthreads();
  {  // Phq write-out from packed Ks: same lane-contiguous mapping
#pragma unroll
    for (int it = 0; it < 8; ++it) {
      int row = (tid >> 4) + it * 16;
      int ch8 = tid & 15;
      int slot = (ch8 < 8) ? ch8 * 4 : 64 + (ch8 - 8) * 4;
      u16x8 o = __builtin_bit_cast(u16x8, *(const f32x4*)&Ks[row][slot]);
      *(u16x8*)(Phq + ((size_t)(c * CH + row) * BB + b) * EE + h * PHI2 + ch8 * 8) = o;
    }
  }
}

// ---------------- pass1 (MFMA): St_c[d][f] = sum_j VbT[d][j]*phik[j][f]
__global__ __launch_bounds__(256) void pass1_mfma(
    const unsigned short* __restrict__ Phk, const unsigned short* __restrict__ VbT,
    unsigned short* __restrict__ St)
{
  __shared__ __align__(16) unsigned short KT[128 * 132];  // [f][j]
  __shared__ __align__(16) unsigned short Am[128 * 40];   // [d][32 j] stream
  const int c = blockIdx.x, b = blockIdx.y, h = blockIdx.z;
  const int tid = threadIdx.x;
  const int w = tid >> 6, l = tid & 63;
  const int wm = (w >> 1) * 64, wn = (w & 1) * 64;
  const int cl = l & 15, ks = l >> 4;
  const int bh = b * HH + h;

  {  // transpose-stage phi_k tile into KT[f][j]
    int j = tid >> 1, f0 = (tid & 1) * 64;
    const unsigned short* gp = Phk + ((size_t)(c * CH + j) * BB + b) * EE + h * PHI2 + f0;
#pragma unroll
    for (int k8 = 0; k8 < 8; ++k8) {
      u16x8 v = *(const u16x8*)(gp + k8 * 8);
#pragma unroll
      for (int e = 0; e < 8; ++e) KT[(f0 + k8 * 8 + e) * 132 + j] = v[e];
    }
  }

  f32x4 acc[4][4] = {};
  const unsigned short* vbase = VbT + (size_t)bh * DD * 4096 + c * CH;
#pragma unroll 1
  for (int j0 = 0; j0 < 128; j0 += 32) {
    __syncthreads();
    stage_rs(vbase + j0, 4096, Am, tid);
    __syncthreads();
    bf16x8 af[4], wf[4];
#pragma unroll
    for (int i = 0; i < 4; ++i) {
      af[i] = ldfrag(Am + (wm + cl + i * 16) * 40 + ks * 8);
      wf[i] = ldfrag64(KT + (wn + cl + i * 16) * 132 + j0 + ks * 8);
    }
#pragma unroll
    for (int i = 0; i < 4; ++i)
#pragma unroll
      for (int j = 0; j < 4; ++j)
        acc[i][j] = __builtin_amdgcn_mfma_f32_16x16x32_bf16(af[i], wf[j], acc[i][j], 0, 0, 0);
  }
  unsigned short* sp = St + (size_t)(bh * NC + c) * (DD * PHI2);
#pragma unroll
  for (int i = 0; i < 4; ++i) {
    int d = wm + i * 16 + ks * 4;
#pragma unroll
    for (int r = 0; r < 4; ++r) {
#pragma unroll
      for (int j = 0; j < 4; ++j)
        sp[(size_t)(d + r) * PHI2 + wn + j * 16 + cl] = f2b(acc[i][j][r]);
    }
  }
}

// ---------------- sscan: exclusive prefix over chunks of St (bf16, fp32 carry)
__global__ __launch_bounds__(256) void sscan_kernel(unsigned short* __restrict__ Sb)
{
  int gid = blockIdx.x * 256 + threadIdx.x;
  if (gid >= 64 * CH * DD) return;
  int bh = gid >> 14, fd = gid & 16383;
  unsigned short* p = Sb + (size_t)bh * NC * 16384 + fd;
  float run = 0.f;
#pragma unroll
  for (int cc = 0; cc < NC; ++cc) {
    float t = b2f(p[(size_t)cc * 16384]);
    p[(size_t)cc * 16384] = f2b(run);
    run += t;
  }
}

// ---------------- attn (MFMA): per (c,b,h)
// sc = phiq @ phik^T (causal); num = sc @ VbT^T + phiq @ St^T; Ob = num / max(Den, eps)
__global__ __launch_bounds__(256) void attn_mfma(
    const unsigned short* __restrict__ Phq, const unsigned short* __restrict__ Phk,
    const unsigned short* __restrict__ VbT, const unsigned short* __restrict__ St,
    const float* __restrict__ Den, unsigned short* __restrict__ Ob)
{
  __shared__ __align__(16) unsigned short Qs[128 * 132];
  __shared__ __align__(16) unsigned short sc[128 * 132];
  __shared__ __align__(16) unsigned short Sm[128 * 40];
  __shared__ float den_s[128];
  const int c = blockIdx.x, b = blockIdx.y, h = blockIdx.z;
  const int tid = threadIdx.x;
  const int w = tid >> 6, l = tid & 63;
  const int wm = (w >> 1) * 64, wn = (w & 1) * 64;
  const int cl = l & 15, ks = l >> 4;
  const int bh = b * HH + h;

  {  // stage phi_q tile
    int r = tid >> 1, f0 = (tid & 1) * 64;
    const unsigned short* gp = Phq + ((size_t)(c * CH + r) * BB + b) * EE + h * PHI2 + f0;
    unsigned short* lp = Qs + r * 132 + f0;
#pragma unroll
    for (int k8 = 0; k8 < 8; ++k8) {
      u16x8 v = *(const u16x8*)(gp + k8 * 8);
      u16x4 vl = __builtin_shufflevector(v, v, 0, 1, 2, 3);
      u16x4 vh = __builtin_shufflevector(v, v, 4, 5, 6, 7);
      *(u16x4*)(lp + k8 * 8) = vl;
      *(u16x4*)(lp + k8 * 8 + 4) = vh;
    }
  }
  if (tid < 128) den_s[tid] = Den[(size_t)bh * TT + c * CH + tid];

  f32x4 acc[4][4] = {};
  // ---- phase A: scores
  const unsigned short* kbase = Phk + ((size_t)(c * CH) * BB + b) * EE + h * PHI2;
#pragma unroll 1
  for (int ft = 0; ft < PHI2; ft += 32) {
    __syncthreads();
    stage_rs(kbase + ft, (size_t)BB * EE, Sm, tid);
    __syncthreads();
    if (w != 1) {  // wave (rows 0-63, cols 64-127) fully masked -> skip
      bf16x8 af[4], wf[4];
#pragma unroll
      for (int i = 0; i < 4; ++i) {
        af[i] = ldfrag64(Qs + (wm + cl + i * 16) * 132 + ft + ks * 8);
        wf[i] = ldfrag(Sm + (wn + cl + i * 16) * 40 + ks * 8);
      }
#pragma unroll
      for (int i = 0; i < 4; ++i)
#pragma unroll
        for (int j = 0; j < 4; ++j)
          acc[i][j] = __builtin_amdgcn_mfma_f32_16x16x32_bf16(af[i], wf[j], acc[i][j], 0, 0, 0);
    }
  }
  __syncthreads();
#pragma unroll
  for (int i = 0; i < 4; ++i) {
    int row0 = wm + i * 16 + ks * 4;
#pragma unroll
    for (int r = 0; r < 4; ++r) {
      int row = row0 + r;
#pragma unroll
      for (int j = 0; j < 4; ++j) {
        int col = wn + j * 16 + cl;
        sc[row * 132 + col] = f2b((col <= row) ? acc[i][j][r] : 0.f);
      }
    }
  }
  __syncthreads();

  // ---- phase B
#pragma unroll
  for (int i = 0; i < 4; ++i)
#pragma unroll
    for (int j = 0; j < 4; ++j) acc[i][j] = (f32x4){0.f, 0.f, 0.f, 0.f};

  const unsigned short* vbase = VbT + (size_t)bh * DD * 4096 + c * CH;
#pragma unroll 1
  for (int j0 = 0; j0 < 128; j0 += 32) {
    __syncthreads();
    stage_rs(vbase + j0, 4096, Sm, tid);
    __syncthreads();
    if (!(wm == 0 && j0 >= 64)) {
      bf16x8 af[4], wf[4];
#pragma unroll
      for (int i = 0; i < 4; ++i) {
        af[i] = ldfrag64(sc + (wm + cl + i * 16) * 132 + j0 + ks * 8);
        wf[i] = ldfrag(Sm + (wn + cl + i * 16) * 40 + ks * 8);
      }
#pragma unroll
      for (int i = 0; i < 4; ++i)
#pragma unroll
        for (int j = 0; j < 4; ++j)
          acc[i][j] = __builtin_amdgcn_mfma_f32_16x16x32_bf16(af[i], wf[j], acc[i][j], 0, 0, 0);
    }
  }
  const unsigned short* sbase = St + (size_t)(bh * NC + c) * (DD * PHI2);
#pragma unroll 1
  for (int f0 = 0; f0 < PHI2; f0 += 32) {
    __syncthreads();
    stage_rs(sbase + f0, PHI2, Sm, tid);
    __syncthreads();
    bf16x8 af[4], wf[4];
#pragma unroll
    for (int i = 0; i < 4; ++i) {
      af[i] = ldfrag64(Qs + (wm + cl + i * 16) * 132 + f0 + ks * 8);
      wf[i] = ldfrag(Sm + (wn + cl + i * 16) * 40 + ks * 8);
    }
#pragma unroll
    for (int i = 0; i < 4; ++i)
#pragma unroll
      for (int j = 0; j < 4; ++j)
        acc[i][j] = __builtin_amdgcn_mfma_f32_16x16x32_bf16(af[i], wf[j], acc[i][j], 0, 0, 0);
  }
#pragma unroll
  for (int i = 0; i < 4; ++i) {
    int row0 = wm + i * 16 + ks * 4;
#pragma unroll
    for (int r = 0; r < 4; ++r) {
      int row = row0 + r;
      float inv = 1.0f / fmaxf(den_s[row], EPSV);
      unsigned short* op = Ob + ((size_t)(c * CH + row) * BB + b) * EE + h * DD;
#pragma unroll
      for (int j = 0; j < 4; ++j)
        op[wn + j * 16 + cl] = f2b(acc[i][j][r] * inv);
    }
  }
}

extern "C" void kernel_launch(void* const* d_in, const int* in_sizes, int n_in,
                              void* d_out, int out_size, void* d_ws, size_t ws_size,
                              hipStream_t stream)
{
  const float* x     = (const float*)d_in[0];
  const float* rmat  = (const float*)d_in[1];
  const float* Wq    = (const float*)d_in[2];
  const float* bq    = (const float*)d_in[3];
  const float* Wk    = (const float*)d_in[4];
  const float* bk    = (const float*)d_in[5];
  const float* Wv    = (const float*)d_in[6];
  const float* bv    = (const float*)d_in[7];
  const float* Wo    = (const float*)d_in[8];
  const float* bo    = (const float*)d_in[9];
  const float* sigma = (const float*)d_in[10];

  // ---- workspace (256 MiB), lifetimes stream-ordered:
  //   [0,  64Mi): pq_p fp32 (steps 4-10)  -> St bf16 (pass1 out, steps 11-13)
  //   [64,128Mi): pk_p fp32 (steps 5-10)  -> Ob bf16 (attn out, steps 13-15)
  //   [128,192Mi): Vb bf16 (steps 6-7)    -> Z1 @128Mi, Den @129Mi, Woh @130Mi, Wol @132Mi
  //   [240,256Mi): Weff fp32 + biases + weight splits (steps 2-6)
  //   [192,256Mi): VbT bf16 (vtrans out, steps 7-13; overwrites weights after step 6)
  // ---- d_out (128 MiB):
  //   xhi [0,64Mi), xlo [64,128Mi) (steps 1-6) -> Phq [0,64Mi), Phk [64,128Mi)
  //   (den2 out, steps 10-13) -> final fp32 output (step 15)
  char* wsb = (char*)d_ws;
  float* pq_p = (float*)wsb;
  float* pk_p = (float*)(wsb + (64LL << 20));
  unsigned short* Stb = (unsigned short*)wsb;
  unsigned short* Ob  = (unsigned short*)(wsb + (64LL << 20));
  unsigned short* Vb  = (unsigned short*)(wsb + (128LL << 20));
  float* Z1  = (float*)(wsb + (128LL << 20));
  float* Den = (float*)(wsb + (129LL << 20));
  unsigned short* Woh = (unsigned short*)(wsb + (130LL << 20));
  unsigned short* Wol = (unsigned short*)(wsb + (132LL << 20));
  unsigned short* VbT = (unsigned short*)(wsb + (192LL << 20));
  float* Weq = (float*)(wsb + (240LL << 20));
  float* Wek = (float*)(wsb + (242LL << 20));
  float* beq = (float*)(wsb + (244LL << 20));
  float* bek = (float*)(wsb + (244LL << 20) + 65536);
  unsigned short* Weqh = (unsigned short*)(wsb + (245LL << 20));
  unsigned short* Weql = (unsigned short*)(wsb + (246LL << 20));
  unsigned short* Wekh = (unsigned short*)(wsb + (247LL << 20));
  unsigned short* Wekl = (unsigned short*)(wsb + (248LL << 20));
  unsigned short* Wvh  = (unsigned short*)(wsb + (249LL << 20));
  unsigned short* Wvl  = (unsigned short*)(wsb + (251LL << 20));

  char* ob = (char*)d_out;
  unsigned short* xhi = (unsigned short*)ob;
  unsigned short* xlo = (unsigned short*)(ob + (64LL << 20));
  unsigned short* Phq = (unsigned short*)ob;
  unsigned short* Phk = (unsigned short*)(ob + (64LL << 20));

  dim3 bt(256);
  // 1-3: casts + effective projection weights + splits
  hipLaunchKernelGGL(split_kernel, dim3(2048), bt, 0, stream, x, xhi, xlo, NROWS * EE / 4);
  hipLaunchKernelGGL(weff_kernel, dim3(8, 8), bt, 0, stream, rmat, sigma, Wq, bq, Weq, beq);
  hipLaunchKernelGGL(weff_kernel, dim3(8, 8), bt, 0, stream, rmat, sigma, Wk, bk, Wek, bek);
  hipLaunchKernelGGL(split_kernel, dim3(512), bt, 0, stream, Weq, Weqh, Weql, NPROJ * EE / 4);
  hipLaunchKernelGGL(split_kernel, dim3(512), bt, 0, stream, Wek, Wekh, Wekl, NPROJ * EE / 4);
  hipLaunchKernelGGL(split_kernel, dim3(1024), bt, 0, stream, Wv, Wvh, Wvl, EE * EE / 4);
  // 4-6: projections (fp32 p for q/k 3-pass; bf16 V 2-pass)
  hipLaunchKernelGGL((gemm_mfma<0, 3>), dim3(NROWS / 128, NPROJ / 128), bt, 0, stream,
                     xhi, xlo, Weqh, Weql, beq, (void*)pq_p, NROWS, NPROJ, EE);
  hipLaunchKernelGGL((gemm_mfma<0, 3>), dim3(NROWS / 128, NPROJ / 128), bt, 0, stream,
                     xhi, xlo, Wekh, Wekl, bek, (void*)pk_p, NROWS, NPROJ, EE);
  hipLaunchKernelGGL((gemm_mfma<1, 2>), dim3(NROWS / 128, EE / 128), bt, 0, stream,
                     xhi, (const unsigned short*)0, Wvh, Wvl, bv, (void*)Vb, NROWS, EE, EE);
  // 7: V transpose (Vb dead after; VbT overwrites weight region — weights dead)
  hipLaunchKernelGGL(vtrans_kernel, dim3(NC, BB, HH), bt, 0, stream, Vb, VbT);
  // 8-10: fp32 denominator path; den2 also emits Phq/Phk bf16 (xhi/xlo dead)
  hipLaunchKernelGGL(den1_kernel, dim3(NC, BB, HH), bt, 0, stream, pk_p, Z1);
  hipLaunchKernelGGL(zscan_kernel, dim3(32), bt, 0, stream, Z1);
  hipLaunchKernelGGL(den2_kernel, dim3(NC, BB, HH), bt, 0, stream, pq_p, pk_p, Z1, Den, Phq, Phk);
  // 11-12: chunk states + exclusive scan (pq_p dead -> St)
  hipLaunchKernelGGL(pass1_mfma, dim3(NC, BB, HH), bt, 0, stream, Phk, VbT, Stb);
  hipLaunchKernelGGL(sscan_kernel, dim3(4096), bt, 0, stream, Stb);
  // 13: attention (pk_p dead -> Ob)
  hipLaunchKernelGGL(attn_mfma, dim3(NC, BB, HH), bt, 0, stream, Phq, Phk, VbT, Stb, Den, Ob);
  // 14-15: output projection
  hipLaunchKernelGGL(split_kernel, dim3(1024), bt, 0, stream, Wo, Woh, Wol, EE * EE / 4);
  hipLaunchKernelGGL((gemm_mfma<0, 2>), dim3(NROWS / 128, EE / 128), bt, 0, stream,
                     Ob, (const unsigned short*)0, Woh, Wol, bo, (void*)d_out, NROWS, EE, EE);
}

// Round 8
// 1073.673 us; speedup vs baseline: 3.3828x; 1.1016x over previous
//
#include <hip/hip_runtime.h>
#include <math.h>

#define TT 4096
#define BB 8
#define EE 1024
#define HH 8
#define DD 128
#define KK 64        // proj dim per head
#define PHI2 128     // 2K features per head
#define PSTR 1024    // merged pre-sincos buffer row stride (q cols 0-511, k cols 512-1023)
#define CH 128
#define NC 32
#define NROWS 32768
#define EPSV 1e-6f

typedef float f32x4 __attribute__((ext_vector_type(4)));
typedef __bf16 bf16x8 __attribute__((ext_vector_type(8)));
typedef unsigned short u16x8 __attribute__((ext_vector_type(8)));
typedef unsigned short u16x4 __attribute__((ext_vector_type(4)));

__device__ __forceinline__ unsigned short f2b(float f) {
  union { float f; unsigned int u; } v; v.f = f;
  unsigned int u = v.u;
  u += 0x7fffu + ((u >> 16) & 1u);
  return (unsigned short)(u >> 16);
}
__device__ __forceinline__ float b2f(unsigned short h) {
  union { float f; unsigned int u; } v; v.u = ((unsigned int)h) << 16;
  return v.f;
}
// native sin/cos: |err| ~1e-6 for |x|<~16 — below bf16 quantum, negligible in fp32 den.
__device__ __forceinline__ void fast_sc(float x, float& s, float& c) {
  s = __sinf(x); c = __cosf(x);
}

// async global->LDS, 16B per lane; lds ptr must be wave-uniform (HW writes base+lane*16).
__device__ __forceinline__ void stage16(const void* g, void* l) {
  __builtin_amdgcn_global_load_lds(
      (const __attribute__((address_space(1))) void*)g,
      (__attribute__((address_space(3))) void*)l, 16, 0, 0);
}

__device__ __forceinline__ bf16x8 ldfrag(const unsigned short* p) {  // 16B-aligned
  u16x8 s = *(const u16x8*)p;
  return __builtin_bit_cast(bf16x8, s);
}
__device__ __forceinline__ bf16x8 ldfrag64(const unsigned short* p) {  // 8B-aligned (pitch-132 LDS)
  u16x4 a = *(const u16x4*)p;
  u16x4 b = *(const u16x4*)(p + 4);
  u16x8 v = {a[0], a[1], a[2], a[3], b[0], b[1], b[2], b[3]};
  return __builtin_bit_cast(bf16x8, v);
}

// stream-stage [128 rows][32 cols] bf16 from global (row stride rstride shorts)
// into LDS pitch 40 (80B rows, 16B-aligned). all 256 threads.
__device__ __forceinline__ void stage_rs(const unsigned short* gbase, size_t rstride,
                                         unsigned short* lds, int tid)
{
  int r = tid >> 1, c0 = (tid & 1) * 16;
  const unsigned short* gp = gbase + (size_t)r * rstride + c0;
  u16x8 v0 = *(const u16x8*)gp;
  u16x8 v1 = *(const u16x8*)(gp + 8);
  *(u16x8*)(lds + r * 40 + c0) = v0;
  *(u16x8*)(lds + r * 40 + c0 + 8) = v1;
}

// ---- split fp32 -> bf16 hi + bf16 lo (residual), vectorized x4
__global__ __launch_bounds__(256) void split_kernel(
    const float* __restrict__ in, unsigned short* __restrict__ hi,
    unsigned short* __restrict__ lo, int n4)
{
  int stride = gridDim.x * 256;
  for (int i = blockIdx.x * 256 + threadIdx.x; i < n4; i += stride) {
    float4 v = ((const float4*)in)[i];
    ushort4 h, l;
    h.x = f2b(v.x); l.x = f2b(v.x - b2f(h.x));
    h.y = f2b(v.y); l.y = f2b(v.y - b2f(h.y));
    h.z = f2b(v.z); l.z = f2b(v.z - b2f(h.z));
    h.w = f2b(v.w); l.w = f2b(v.w - b2f(h.w));
    ((ushort4*)hi)[i] = h;
    ((ushort4*)lo)[i] = l;
  }
}

// ---- Weff[h*64+k][e] = sum_d s4*sigma[h,d]*rm[h,k,d]*W[h*128+d][e]; beff likewise from b.
__global__ __launch_bounds__(256) void weff_kernel(
    const float* __restrict__ rmat, const float* __restrict__ sigma,
    const float* __restrict__ W, const float* __restrict__ bvec,
    float* __restrict__ Weff, float* __restrict__ beff)
{
  __shared__ float rme[64][130];
  __shared__ float Wt[128][130];
  const int et = blockIdx.x;
  const int h  = blockIdx.y;
  const int tid = threadIdx.x;
  const int e0 = et * 128;
  const float s4 = 0.29730177875068026f;  // 128^-0.25

  for (int f = tid; f < 64 * 32; f += 256) {
    int kk = f >> 5, d = (f & 31) * 4;
    float4 rv = *(const float4*)(rmat + ((size_t)(h * 64 + kk)) * 128 + d);
    const float* sg = sigma + h * 128 + d;
    rme[kk][d + 0] = rv.x * sg[0] * s4;
    rme[kk][d + 1] = rv.y * sg[1] * s4;
    rme[kk][d + 2] = rv.z * sg[2] * s4;
    rme[kk][d + 3] = rv.w * sg[3] * s4;
  }
  for (int f = tid; f < 128 * 32; f += 256) {
    int dd = f >> 5, e = (f & 31) * 4;
    *(float4*)&Wt[dd][e] = *(const float4*)(W + ((size_t)(h * 128 + dd)) * EE + e0 + e);
  }
  __syncthreads();
  const int nl = tid >> 2;
  const int el0 = (tid & 3) * 32;
  for (int e = 0; e < 32; ++e) {
    float acc = 0.f;
#pragma unroll
    for (int d = 0; d < 128; ++d)
      acc = fmaf(rme[nl][d], Wt[d][el0 + e], acc);
    Weff[(size_t)(h * 64 + nl) * EE + e0 + el0 + e] = acc;
  }
  if (et == 0 && tid < 64) {
    float acc = 0.f;
    for (int d = 0; d < 128; ++d)
      acc = fmaf(rme[tid][d], bvec[h * 128 + d], acc);
    beff[h * 64 + tid] = acc;
  }
}

// ---------------- MFMA GEMM: C[M,N] = A[M,K] @ W[N,K]^T + bias[N]
// fp32 split compensation fused in one K-loop:
//   NPASS=3: acc += Ahi*Whi + Ahi*Wlo + Alo*Whi   (den-feeding Q/K path, full fidelity)
//   NPASS=1: acc += Ahi*Whi                        (num path; error ~1e-3 rel ~ bf16 rounding)
// m97 structure: 128x128 tile, BK=32, 4 waves (2x2), 4x4 16x16x32 frags/wave.
// Grid is XCD-swizzled (bijective; requires gridDim.x % 8 == 0).
template<int OUTBF16, int NPASS>
__global__ __launch_bounds__(256) void gemm_mfma(
    const unsigned short* __restrict__ Ahi, const unsigned short* __restrict__ Alo,
    const unsigned short* __restrict__ Whi, const unsigned short* __restrict__ Wlo,
    const float* __restrict__ bias, void* __restrict__ Cout, int M, int N, int Kd)
{
  __shared__ __align__(16) unsigned short Ahs[128 * 32];
  __shared__ __align__(16) unsigned short Whs[128 * 32];
  __shared__ __align__(16) unsigned short Wls[(NPASS >= 2) ? 128 * 32 : 8];
  __shared__ __align__(16) unsigned short Als[(NPASS == 3) ? 128 * 32 : 8];
  const int tid = threadIdx.x;
  const int w = tid >> 6, l = tid & 63;
  // XCD-aware bijective swizzle: same-M-tile blocks adjacent on one XCD.
  int bx, by;
  {
    int id = blockIdx.x + gridDim.x * blockIdx.y;
    int xcd = id & 7, k = id >> 3;
    by = k % gridDim.y;
    bx = xcd * (gridDim.x >> 3) + k / gridDim.y;
  }
  const int m0 = bx * 128, n0 = by * 128;
  const int wm = (w >> 1) * 64, wn = (w & 1) * 64;
  const int rowA = tid >> 2, ko = (tid & 3) * 8;

  f32x4 acc[4][4] = {};
  const int sb0 = w * 512, sb1 = 2048 + w * 512;
  const int fA = (wm + (l & 15)) * 32 + (l >> 4) * 8;
  const int fW = (wn + (l & 15)) * 32 + (l >> 4) * 8;

  const unsigned short* gah0 = Ahi + (size_t)(m0 + rowA) * Kd + ko;
  const unsigned short* gah1 = Ahi + (size_t)(m0 + 64 + rowA) * Kd + ko;
  const unsigned short* gwh0 = Whi + (size_t)(n0 + rowA) * Kd + ko;
  const unsigned short* gwh1 = Whi + (size_t)(n0 + 64 + rowA) * Kd + ko;
  const unsigned short* gwl0 = nullptr;
  const unsigned short* gwl1 = nullptr;
  if (NPASS >= 2) {
    gwl0 = Wlo + (size_t)(n0 + rowA) * Kd + ko;
    gwl1 = Wlo + (size_t)(n0 + 64 + rowA) * Kd + ko;
  }
  const unsigned short* gal0 = nullptr;
  const unsigned short* gal1 = nullptr;
  if (NPASS == 3) {
    gal0 = Alo + (size_t)(m0 + rowA) * Kd + ko;
    gal1 = Alo + (size_t)(m0 + 64 + rowA) * Kd + ko;
  }

#pragma unroll 1
  for (int kt = 0; kt < Kd; kt += 32) {
    __syncthreads();
    stage16(gah0 + kt, Ahs + sb0);
    stage16(gah1 + kt, Ahs + sb1);
    stage16(gwh0 + kt, Whs + sb0);
    stage16(gwh1 + kt, Whs + sb1);
    if (NPASS >= 2) {
      stage16(gwl0 + kt, Wls + sb0);
      stage16(gwl1 + kt, Wls + sb1);
    }
    if (NPASS == 3) {
      stage16(gal0 + kt, Als + sb0);
      stage16(gal1 + kt, Als + sb1);
    }
    __syncthreads();
    bf16x8 ah[4], wh[4];
#pragma unroll
    for (int i = 0; i < 4; ++i) {
      ah[i] = ldfrag(Ahs + fA + i * 512);
      wh[i] = ldfrag(Whs + fW + i * 512);
    }
#pragma unroll
    for (int i = 0; i < 4; ++i)
#pragma unroll
      for (int j = 0; j < 4; ++j)
        acc[i][j] = __builtin_amdgcn_mfma_f32_16x16x32_bf16(ah[i], wh[j], acc[i][j], 0, 0, 0);
    if (NPASS >= 2) {
      bf16x8 wl[4];
#pragma unroll
      for (int i = 0; i < 4; ++i) wl[i] = ldfrag(Wls + fW + i * 512);
#pragma unroll
      for (int i = 0; i < 4; ++i)
#pragma unroll
        for (int j = 0; j < 4; ++j)
          acc[i][j] = __builtin_amdgcn_mfma_f32_16x16x32_bf16(ah[i], wl[j], acc[i][j], 0, 0, 0);
    }
    if (NPASS == 3) {
      bf16x8 al[4], whx[4];
#pragma unroll
      for (int i = 0; i < 4; ++i) {
        al[i] = ldfrag(Als + fA + i * 512);
        whx[i] = ldfrag(Whs + fW + i * 512);
      }
#pragma unroll
      for (int i = 0; i < 4; ++i)
#pragma unroll
        for (int j = 0; j < 4; ++j)
          acc[i][j] = __builtin_amdgcn_mfma_f32_16x16x32_bf16(al[i], whx[j], acc[i][j], 0, 0, 0);
    }
  }

  const int cl = l & 15, rg = (l >> 4) * 4;
  float bvv[4];
#pragma unroll
  for (int j = 0; j < 4; ++j) bvv[j] = bias[n0 + wn + j * 16 + cl];
#pragma unroll
  for (int i = 0; i < 4; ++i) {
    const int row = m0 + wm + i * 16 + rg;
#pragma unroll
    for (int r = 0; r < 4; ++r) {
#pragma unroll
      for (int j = 0; j < 4; ++j) {
        float v = acc[i][j][r] + bvv[j];
        if (OUTBF16) {
          ((unsigned short*)Cout)[(size_t)(row + r) * N + n0 + wn + j * 16 + cl] = f2b(v);
        } else {
          ((float*)Cout)[(size_t)(row + r) * N + n0 + wn + j * 16 + cl] = v;
        }
      }
    }
  }
}

// ---------------- Vb [t*8+b][h*128+d] -> VbT [(b*8+h)*128+d][t]
__global__ __launch_bounds__(256) void vtrans_kernel(
    const unsigned short* __restrict__ Vb, unsigned short* __restrict__ VbT)
{
  __shared__ __align__(16) unsigned short T[128 * 132];
  const int tt = blockIdx.x, b = blockIdx.y, h = blockIdx.z;
  const int tid = threadIdx.x;
  {
    int t = tid >> 1, f0 = (tid & 1) * 64;
    const unsigned short* gp = Vb + ((size_t)((tt * 128 + t) * BB + b)) * EE + h * DD + f0;
    unsigned short* lp = T + t * 132 + f0;
#pragma unroll
    for (int k8 = 0; k8 < 8; ++k8) {
      u16x8 v = *(const u16x8*)(gp + k8 * 8);
      u16x4 vl = __builtin_shufflevector(v, v, 0, 1, 2, 3);
      u16x4 vh = __builtin_shufflevector(v, v, 4, 5, 6, 7);
      *(u16x4*)(lp + k8 * 8) = vl;
      *(u16x4*)(lp + k8 * 8 + 4) = vh;
    }
  }
  __syncthreads();
  const size_t obase = ((size_t)(b * HH + h) * DD) * 4096 + tt * 128;
#pragma unroll
  for (int dd = 0; dd < 4; ++dd) {
    int d = (tid >> 3) + dd * 32;
    int t0 = (tid & 7) * 16;
    u16x8 o0, o1;
#pragma unroll
    for (int e = 0; e < 8; ++e) {
      o0[e] = T[(t0 + e) * 132 + d];
      o1[e] = T[(t0 + 8 + e) * 132 + d];
    }
    *(u16x8*)(VbT + obase + (size_t)d * 4096 + t0) = o0;
    *(u16x8*)(VbT + obase + (size_t)d * 4096 + t0 + 8) = o1;
  }
}

// ---------------- den1: Z1[(bh*NC+c)*128 + f] = sum_{j in chunk} phik[j][f]  (fp32)
__global__ __launch_bounds__(256) void den1_kernel(
    const float* __restrict__ Pk, float* __restrict__ Z1)
{
  __shared__ float red[4][130];
  const int c = blockIdx.x, b = blockIdx.y, h = blockIdx.z;
  const int tid = threadIdx.x;
  const int k = tid & 63, part = tid >> 6;
  float ss = 0.f, cs = 0.f;
  const float* pb = Pk + ((size_t)(c * CH) * BB + b) * PSTR + h * KK + k;
  for (int j = part * 32; j < part * 32 + 32; ++j) {
    float p = pb[(size_t)j * BB * PSTR];
    float sv, cv; fast_sc(p, sv, cv);
    ss += sv; cs += cv;
  }
  red[part][k] = ss * 0.125f;
  red[part][k + 65] = cs * 0.125f;
  __syncthreads();
  if (tid < 128) {
    int f = tid;
    int idx = (f < 64) ? f : (f + 1);
    float s = red[0][idx] + red[1][idx] + red[2][idx] + red[3][idx];
    Z1[((size_t)(b * HH + h) * NC + c) * 128 + f] = s;
  }
}

// ---------------- zscan: exclusive prefix of Z1 over chunks, per (bh, f)
__global__ __launch_bounds__(256) void zscan_kernel(float* __restrict__ Z1)
{
  int gid = blockIdx.x * 256 + threadIdx.x;
  if (gid >= 64 * 128) return;
  int bh = gid >> 7, f = gid & 127;
  float* p = Z1 + (size_t)bh * NC * 128 + f;
  float run = 0.f;
#pragma unroll
  for (int cc = 0; cc < NC; ++cc) {
    float t = p[cc * 128];
    p[cc * 128] = run;
    run += t;
  }
}

// ---------------- den2: Den[bh*TT + c*128 + row] = phiq[row] . (Z1_prefix + cumsum_{j<=row} phik[j])
// Byproducts: Phk, Phq bf16 buffers, written lane-contiguous (full-sector stores).
__global__ __launch_bounds__(256) void den2_kernel(
    const float* __restrict__ Pq, const float* __restrict__ Pk,
    const float* __restrict__ Z1, float* __restrict__ Den,
    unsigned short* __restrict__ Phq, unsigned short* __restrict__ Phk)
{
  __shared__ float Ks[128][132];
  const int c = blockIdx.x, b = blockIdx.y, h = blockIdx.z;
  const int tid = threadIdx.x;
  const int bh = b * HH + h;
  {  // phase 1: Ks[j][f] = phik[j][f] (LDS only)
    int j = tid >> 1, k0 = (tid & 1) * 32;
    const float* pp = Pk + ((size_t)(c * CH + j) * BB + b) * PSTR + h * KK + k0;
#pragma unroll
    for (int k4 = 0; k4 < 32; k4 += 4) {
      float4 p = *(const float4*)(pp + k4);
      float sv, cv;
      fast_sc(p.x, sv, cv); Ks[j][k0 + k4 + 0] = sv * 0.125f; Ks[j][64 + k0 + k4 + 0] = cv * 0.125f;
      fast_sc(p.y, sv, cv); Ks[j][k0 + k4 + 1] = sv * 0.125f; Ks[j][64 + k0 + k4 + 1] = cv * 0.125f;
      fast_sc(p.z, sv, cv); Ks[j][k0 + k4 + 2] = sv * 0.125f; Ks[j][64 + k0 + k4 + 2] = cv * 0.125f;
      fast_sc(p.w, sv, cv); Ks[j][k0 + k4 + 3] = sv * 0.125f; Ks[j][64 + k0 + k4 + 3] = cv * 0.125f;
    }
  }
  __syncthreads();
  {  // Phk write-out: 16 lanes cover one row's 16x16B chunks -> 256B contiguous per row
#pragma unroll
    for (int it = 0; it < 8; ++it) {
      int row = (tid >> 4) + it * 16;
      int ch8 = tid & 15;
      f32x4 a = *(const f32x4*)&Ks[row][ch8 * 8];
      f32x4 bb = *(const f32x4*)&Ks[row][ch8 * 8 + 4];
      u16x8 o;
      o[0] = f2b(a[0]); o[1] = f2b(a[1]); o[2] = f2b(a[2]); o[3] = f2b(a[3]);
      o[4] = f2b(bb[0]); o[5] = f2b(bb[1]); o[6] = f2b(bb[2]); o[7] = f2b(bb[3]);
      *(u16x8*)(Phk + ((size_t)(c * CH + row) * BB + b) * EE + h * PHI2 + ch8 * 8) = o;
    }
  }
  __syncthreads();
  if (tid < 128) {  // phase 2: inclusive cumsum down j, seeded with exclusive chunk prefix
    int f = tid;
    float run = Z1[((size_t)bh * NC + c) * 128 + f];
    for (int j = 0; j < 128; ++j) { run += Ks[j][f]; Ks[j][f] = run; }
  }
  __syncthreads();
  {  // phase 3: den[row] = sum_f phiq[row][f] * Ks[row][f];
     // pack phiq bf16 pairs in place into the consumed prefix of Ks[row] (forward pack).
    int row = tid >> 1, half = tid & 1;
    const float* pq = Pq + ((size_t)(c * CH + row) * BB + b) * PSTR + h * KK;
    float accd = 0.f;
#pragma unroll
    for (int k8 = 0; k8 < 8; ++k8) {
      float4 p0 = *(const float4*)(pq + k8 * 8);
      float4 p1 = *(const float4*)(pq + k8 * 8 + 4);
      float ph[8];
      float sv, cv;
      fast_sc(p0.x, sv, cv); ph[0] = (half ? cv : sv) * 0.125f;
      fast_sc(p0.y, sv, cv); ph[1] = (half ? cv : sv) * 0.125f;
      fast_sc(p0.z, sv, cv); ph[2] = (half ? cv : sv) * 0.125f;
      fast_sc(p0.w, sv, cv); ph[3] = (half ? cv : sv) * 0.125f;
      fast_sc(p1.x, sv, cv); ph[4] = (half ? cv : sv) * 0.125f;
      fast_sc(p1.y, sv, cv); ph[5] = (half ? cv : sv) * 0.125f;
      fast_sc(p1.z, sv, cv); ph[6] = (half ? cv : sv) * 0.125f;
      fast_sc(p1.w, sv, cv); ph[7] = (half ? cv : sv) * 0.125f;
#pragma unroll
      for (int e = 0; e < 8; ++e)
        accd = fmaf(ph[e], Ks[row][half * 64 + k8 * 8 + e], accd);
      // pack 8 phi -> 4 uints at slots [half*64 + k8*4, +4): below all future reads
      float* dst = &Ks[row][half * 64 + k8 * 4];
#pragma unroll
      for (int e2 = 0; e2 < 4; ++e2) {
        unsigned int pk = (unsigned int)f2b(ph[2 * e2]) |
                          ((unsigned int)f2b(ph[2 * e2 + 1]) << 16);
        dst[e2] = __builtin_bit_cast(float, pk);
      }
    }
    accd += __shfl_xor(accd, 1);
    if (half == 0) Den[(size_t)bh * TT + c * CH + row] = accd;
  }
  __syncthreads();
  {  // Phq write-out from packed Ks: same lane-contiguous mapping
#pragma unroll
    for (int it = 0; it < 8; ++it) {
      int row = (tid >> 4) + it * 16;
      int ch8 = tid & 15;
      int slot = (ch8 < 8) ? ch8 * 4 : 64 + (ch8 - 8) * 4;
      u16x8 o = __builtin_bit_cast(u16x8, *(const f32x4*)&Ks[row][slot]);
      *(u16x8*)(Phq + ((size_t)(c * CH + row) * BB + b) * EE + h * PHI2 + ch8 * 8) = o;
    }
  }
}

// ---------------- pass1 (MFMA): St_c[d][f] = sum_j VbT[d][j]*phik[j][f]
__global__ __launch_bounds__(256) void pass1_mfma(
    const unsigned short* __restrict__ Phk, const unsigned short* __restrict__ VbT,
    unsigned short* __restrict__ St)
{
  __shared__ __align__(16) unsigned short KT[128 * 132];  // [f][j]
  __shared__ __align__(16) unsigned short Am[128 * 40];   // [d][32 j] stream
  const int c = blockIdx.x, b = blockIdx.y, h = blockIdx.z;
  const int tid = threadIdx.x;
  const int w = tid >> 6, l = tid & 63;
  const int wm = (w >> 1) * 64, wn = (w & 1) * 64;
  const int cl = l & 15, ks = l >> 4;
  const int bh = b * HH + h;

  {  // transpose-stage phi_k tile into KT[f][j]
    int j = tid >> 1, f0 = (tid & 1) * 64;
    const unsigned short* gp = Phk + ((size_t)(c * CH + j) * BB + b) * EE + h * PHI2 + f0;
#pragma unroll
    for (int k8 = 0; k8 < 8; ++k8) {
      u16x8 v = *(const u16x8*)(gp + k8 * 8);
#pragma unroll
      for (int e = 0; e < 8; ++e) KT[(f0 + k8 * 8 + e) * 132 + j] = v[e];
    }
  }

  f32x4 acc[4][4] = {};
  const unsigned short* vbase = VbT + (size_t)bh * DD * 4096 + c * CH;
#pragma unroll 1
  for (int j0 = 0; j0 < 128; j0 += 32) {
    __syncthreads();
    stage_rs(vbase + j0, 4096, Am, tid);
    __syncthreads();
    bf16x8 af[4], wf[4];
#pragma unroll
    for (int i = 0; i < 4; ++i) {
      af[i] = ldfrag(Am + (wm + cl + i * 16) * 40 + ks * 8);
      wf[i] = ldfrag64(KT + (wn + cl + i * 16) * 132 + j0 + ks * 8);
    }
#pragma unroll
    for (int i = 0; i < 4; ++i)
#pragma unroll
      for (int j = 0; j < 4; ++j)
        acc[i][j] = __builtin_amdgcn_mfma_f32_16x16x32_bf16(af[i], wf[j], acc[i][j], 0, 0, 0);
  }
  unsigned short* sp = St + (size_t)(bh * NC + c) * (DD * PHI2);
#pragma unroll
  for (int i = 0; i < 4; ++i) {
    int d = wm + i * 16 + ks * 4;
#pragma unroll
    for (int r = 0; r < 4; ++r) {
#pragma unroll
      for (int j = 0; j < 4; ++j)
        sp[(size_t)(d + r) * PHI2 + wn + j * 16 + cl] = f2b(acc[i][j][r]);
    }
  }
}

// ---------------- sscan: exclusive prefix over chunks of St (bf16, fp32 carry)
__global__ __launch_bounds__(256) void sscan_kernel(unsigned short* __restrict__ Sb)
{
  int gid = blockIdx.x * 256 + threadIdx.x;
  if (gid >= 64 * CH * DD) return;
  int bh = gid >> 14, fd = gid & 16383;
  unsigned short* p = Sb + (size_t)bh * NC * 16384 + fd;
  float run = 0.f;
#pragma unroll
  for (int cc = 0; cc < NC; ++cc) {
    float t = b2f(p[(size_t)cc * 16384]);
    p[(size_t)cc * 16384] = f2b(run);
    run += t;
  }
}

// ---------------- attn (MFMA): per (c,b,h)
// sc = phiq @ phik^T (causal); num = sc @ VbT^T + phiq @ St^T; Ob = num / max(Den, eps)
__global__ __launch_bounds__(256) void attn_mfma(
    const unsigned short* __restrict__ Phq, const unsigned short* __restrict__ Phk,
    const unsigned short* __restrict__ VbT, const unsigned short* __restrict__ St,
    const float* __restrict__ Den, unsigned short* __restrict__ Ob)
{
  __shared__ __align__(16) unsigned short Qs[128 * 132];
  __shared__ __align__(16) unsigned short sc[128 * 132];
  __shared__ __align__(16) unsigned short Sm[128 * 40];
  __shared__ float den_s[128];
  const int c = blockIdx.x, b = blockIdx.y, h = blockIdx.z;
  const int tid = threadIdx.x;
  const int w = tid >> 6, l = tid & 63;
  const int wm = (w >> 1) * 64, wn = (w & 1) * 64;
  const int cl = l & 15, ks = l >> 4;
  const int bh = b * HH + h;

  {  // stage phi_q tile
    int r = tid >> 1, f0 = (tid & 1) * 64;
    const unsigned short* gp = Phq + ((size_t)(c * CH + r) * BB + b) * EE + h * PHI2 + f0;
    unsigned short* lp = Qs + r * 132 + f0;
#pragma unroll
    for (int k8 = 0; k8 < 8; ++k8) {
      u16x8 v = *(const u16x8*)(gp + k8 * 8);
      u16x4 vl = __builtin_shufflevector(v, v, 0, 1, 2, 3);
      u16x4 vh = __builtin_shufflevector(v, v, 4, 5, 6, 7);
      *(u16x4*)(lp + k8 * 8) = vl;
      *(u16x4*)(lp + k8 * 8 + 4) = vh;
    }
  }
  if (tid < 128) den_s[tid] = Den[(size_t)bh * TT + c * CH + tid];

  f32x4 acc[4][4] = {};
  // ---- phase A: scores
  const unsigned short* kbase = Phk + ((size_t)(c * CH) * BB + b) * EE + h * PHI2;
#pragma unroll 1
  for (int ft = 0; ft < PHI2; ft += 32) {
    __syncthreads();
    stage_rs(kbase + ft, (size_t)BB * EE, Sm, tid);
    __syncthreads();
    if (w != 1) {  // wave (rows 0-63, cols 64-127) fully masked -> skip
      bf16x8 af[4], wf[4];
#pragma unroll
      for (int i = 0; i < 4; ++i) {
        af[i] = ldfrag64(Qs + (wm + cl + i * 16) * 132 + ft + ks * 8);
        wf[i] = ldfrag(Sm + (wn + cl + i * 16) * 40 + ks * 8);
      }
#pragma unroll
      for (int i = 0; i < 4; ++i)
#pragma unroll
        for (int j = 0; j < 4; ++j)
          acc[i][j] = __builtin_amdgcn_mfma_f32_16x16x32_bf16(af[i], wf[j], acc[i][j], 0, 0, 0);
    }
  }
  __syncthreads();
#pragma unroll
  for (int i = 0; i < 4; ++i) {
    int row0 = wm + i * 16 + ks * 4;
#pragma unroll
    for (int r = 0; r < 4; ++r) {
      int row = row0 + r;
#pragma unroll
      for (int j = 0; j < 4; ++j) {
        int col = wn + j * 16 + cl;
        sc[row * 132 + col] = f2b((col <= row) ? acc[i][j][r] : 0.f);
      }
    }
  }
  __syncthreads();

  // ---- phase B
#pragma unroll
  for (int i = 0; i < 4; ++i)
#pragma unroll
    for (int j = 0; j < 4; ++j) acc[i][j] = (f32x4){0.f, 0.f, 0.f, 0.f};

  const unsigned short* vbase = VbT + (size_t)bh * DD * 4096 + c * CH;
#pragma unroll 1
  for (int j0 = 0; j0 < 128; j0 += 32) {
    __syncthreads();
    stage_rs(vbase + j0, 4096, Sm, tid);
    __syncthreads();
    if (!(wm == 0 && j0 >= 64)) {
      bf16x8 af[4], wf[4];
#pragma unroll
      for (int i = 0; i < 4; ++i) {
        af[i] = ldfrag64(sc + (wm + cl + i * 16) * 132 + j0 + ks * 8);
        wf[i] = ldfrag(Sm + (wn + cl + i * 16) * 40 + ks * 8);
      }
#pragma unroll
      for (int i = 0; i < 4; ++i)
#pragma unroll
        for (int j = 0; j < 4; ++j)
          acc[i][j] = __builtin_amdgcn_mfma_f32_16x16x32_bf16(af[i], wf[j], acc[i][j], 0, 0, 0);
    }
  }
  const unsigned short* sbase = St + (size_t)(bh * NC + c) * (DD * PHI2);
#pragma unroll 1
  for (int f0 = 0; f0 < PHI2; f0 += 32) {
    __syncthreads();
    stage_rs(sbase + f0, PHI2, Sm, tid);
    __syncthreads();
    bf16x8 af[4], wf[4];
#pragma unroll
    for (int i = 0; i < 4; ++i) {
      af[i] = ldfrag64(Qs + (wm + cl + i * 16) * 132 + f0 + ks * 8);
      wf[i] = ldfrag(Sm + (wn + cl + i * 16) * 40 + ks * 8);
    }
#pragma unroll
    for (int i = 0; i < 4; ++i)
#pragma unroll
      for (int j = 0; j < 4; ++j)
        acc[i][j] = __builtin_amdgcn_mfma_f32_16x16x32_bf16(af[i], wf[j], acc[i][j], 0, 0, 0);
  }
#pragma unroll
  for (int i = 0; i < 4; ++i) {
    int row0 = wm + i * 16 + ks * 4;
#pragma unroll
    for (int r = 0; r < 4; ++r) {
      int row = row0 + r;
      float inv = 1.0f / fmaxf(den_s[row], EPSV);
      unsigned short* op = Ob + ((size_t)(c * CH + row) * BB + b) * EE + h * DD;
#pragma unroll
      for (int j = 0; j < 4; ++j)
        op[wn + j * 16 + cl] = f2b(acc[i][j][r] * inv);
    }
  }
}

extern "C" void kernel_launch(void* const* d_in, const int* in_sizes, int n_in,
                              void* d_out, int out_size, void* d_ws, size_t ws_size,
                              hipStream_t stream)
{
  const float* x     = (const float*)d_in[0];
  const float* rmat  = (const float*)d_in[1];
  const float* Wq    = (const float*)d_in[2];
  const float* bq    = (const float*)d_in[3];
  const float* Wk    = (const float*)d_in[4];
  const float* bk    = (const float*)d_in[5];
  const float* Wv    = (const float*)d_in[6];
  const float* bv    = (const float*)d_in[7];
  const float* Wo    = (const float*)d_in[8];
  const float* bo    = (const float*)d_in[9];
  const float* sigma = (const float*)d_in[10];

  // ---- workspace (256 MiB), lifetimes stream-ordered:
  //   [0, 128Mi): Pqk fp32 [32768][1024] (q cols 0-511, k cols 512-1023; steps 4-9)
  //               -> St bf16 @ [0,64Mi) (pass1, steps 10-12) ; Ob bf16 @ [64,128Mi) (attn, 12-14)
  //   [128,192Mi): Vb bf16 (steps 5-6) -> Z1 @128Mi, Den @129Mi, Woh @130Mi, Wol @132Mi
  //   [240,256Mi): Weqk fp32 [1024][1024] + beqk + Wqkh/Wqkl + Wvh/Wvl (steps 2-5)
  //   [192,256Mi): VbT bf16 (vtrans out, steps 6-12; overwrites weights after step 5)
  // ---- d_out (128 MiB):
  //   xhi [0,64Mi), xlo [64,128Mi) (steps 1-5) -> Phq [0,64Mi), Phk [64,128Mi)
  //   (den2 out, steps 9-12) -> final fp32 output (step 14)
  char* wsb = (char*)d_ws;
  float* Pqk = (float*)wsb;
  float* pq_p = Pqk;
  float* pk_p = Pqk + 512;
  unsigned short* Stb = (unsigned short*)wsb;
  unsigned short* Ob  = (unsigned short*)(wsb + (64LL << 20));
  unsigned short* Vb  = (unsigned short*)(wsb + (128LL << 20));
  float* Z1  = (float*)(wsb + (128LL << 20));
  float* Den = (float*)(wsb + (129LL << 20));
  unsigned short* Woh = (unsigned short*)(wsb + (130LL << 20));
  unsigned short* Wol = (unsigned short*)(wsb + (132LL << 20));
  unsigned short* VbT = (unsigned short*)(wsb + (192LL << 20));
  float* Weqk = (float*)(wsb + (240LL << 20));            // 4 MiB [1024][1024]
  float* beqk = (float*)(wsb + (244LL << 20));            // 4 KiB [1024]
  unsigned short* Wqkh = (unsigned short*)(wsb + (245LL << 20));  // 2 MiB
  unsigned short* Wqkl = (unsigned short*)(wsb + (247LL << 20));  // 2 MiB
  unsigned short* Wvh  = (unsigned short*)(wsb + (249LL << 20));  // 2 MiB
  unsigned short* Wvl  = (unsigned short*)(wsb + (251LL << 20));  // 2 MiB (unused by 1-pass)

  char* ob = (char*)d_out;
  unsigned short* xhi = (unsigned short*)ob;
  unsigned short* xlo = (unsigned short*)(ob + (64LL << 20));
  unsigned short* Phq = (unsigned short*)ob;
  unsigned short* Phk = (unsigned short*)(ob + (64LL << 20));

  dim3 bt(256);
  // 1-3: casts + effective projection weights (Q rows 0-511, K rows 512-1023) + splits
  hipLaunchKernelGGL(split_kernel, dim3(2048), bt, 0, stream, x, xhi, xlo, NROWS * EE / 4);
  hipLaunchKernelGGL(weff_kernel, dim3(8, 8), bt, 0, stream, rmat, sigma, Wq, bq, Weqk, beqk);
  hipLaunchKernelGGL(weff_kernel, dim3(8, 8), bt, 0, stream, rmat, sigma, Wk, bk,
                     Weqk + (size_t)512 * EE, beqk + 512);
  hipLaunchKernelGGL(split_kernel, dim3(1024), bt, 0, stream, Weqk, Wqkh, Wqkl, 1024 * EE / 4);
  hipLaunchKernelGGL(split_kernel, dim3(1024), bt, 0, stream, Wv, Wvh, Wvl, EE * EE / 4);
  // 4: merged Q+K pre-sincos projection (3-pass split, fp32 out) — den-feeding, full fidelity
  hipLaunchKernelGGL((gemm_mfma<0, 3>), dim3(NROWS / 128, 1024 / 128), bt, 0, stream,
                     xhi, xlo, Wqkh, Wqkl, beqk, (void*)Pqk, NROWS, 1024, EE);
  // 5: V projection (1-pass: error ~1e-3 rel, same order as bf16 output rounding)
  hipLaunchKernelGGL((gemm_mfma<1, 1>), dim3(NROWS / 128, EE / 128), bt, 0, stream,
                     xhi, (const unsigned short*)0, Wvh, Wvh, bv, (void*)Vb, NROWS, EE, EE);
  // 6: V transpose (Vb dead after; VbT overwrites weight region — weights dead)
  hipLaunchKernelGGL(vtrans_kernel, dim3(NC, BB, HH), bt, 0, stream, Vb, VbT);
  // 7-9: fp32 denominator path; den2 also emits Phq/Phk bf16 (xhi/xlo dead)
  hipLaunchKernelGGL(den1_kernel, dim3(NC, BB, HH), bt, 0, stream, pk_p, Z1);
  hipLaunchKernelGGL(zscan_kernel, dim3(32), bt, 0, stream, Z1);
  hipLaunchKernelGGL(den2_kernel, dim3(NC, BB, HH), bt, 0, stream, pq_p, pk_p, Z1, Den, Phq, Phk);
  // 10-11: chunk states + exclusive scan (Pqk dead -> St)
  hipLaunchKernelGGL(pass1_mfma, dim3(NC, BB, HH), bt, 0, stream, Phk, VbT, Stb);
  hipLaunchKernelGGL(sscan_kernel, dim3(4096), bt, 0, stream, Stb);
  // 12: attention (-> Ob)
  hipLaunchKernelGGL(attn_mfma, dim3(NC, BB, HH), bt, 0, stream, Phq, Phk, VbT, Stb, Den, Ob);
  // 13-14: output projection (1-pass on Wo hi; A is bf16 already)
  hipLaunchKernelGGL(split_kernel, dim3(1024), bt, 0, stream, Wo, Woh, Wol, EE * EE / 4);
  hipLaunchKernelGGL((gemm_mfma<0, 1>), dim3(NROWS / 128, EE / 128), bt, 0, stream,
                     Ob, (const unsigned short*)0, Woh, Woh, bo, (void*)d_out, NROWS, EE, EE);
}